// Round 14
// baseline (885.947 us; speedup 1.0000x reference)
//
#include <hip/hip_runtime.h>
#include <hip/hip_bf16.h>
#include <cstdint>

#define DEV_INLINE __device__ __forceinline__

using u16 = unsigned short;
typedef __attribute__((ext_vector_type(8))) short bf8_t;   // 8 x bf16 (4 VGPR)
typedef __attribute__((ext_vector_type(4))) float f32x4;

constexpr int cB = 16, cM = 80, cRPI = 256;
constexpr int cN = cB * cM;        // 1280
constexpr int cR = cB * cRPI;      // 4096
constexpr int cDF = 12544, cREP = 1024, cEMB = 256, cHID = 512, cNH = 8, cL = 4;
constexpr int cRELC = 51;

DEV_INLINE u16 f2bf(float x) { return __builtin_bit_cast(u16, __float2bfloat16(x)); }
DEV_INLINE float bf2f(u16 u) { return __bfloat162float(__builtin_bit_cast(__hip_bfloat16, u)); }

DEV_INLINE bf8_t cvt8(float4 a, float4 b) {
  bf8_t r;
  r[0] = (short)f2bf(a.x); r[1] = (short)f2bf(a.y);
  r[2] = (short)f2bf(a.z); r[3] = (short)f2bf(a.w);
  r[4] = (short)f2bf(b.x); r[5] = (short)f2bf(b.y);
  r[6] = (short)f2bf(b.z); r[7] = (short)f2bf(b.w);
  return r;
}

DEV_INLINE float wave_max(float v) {
#pragma unroll
  for (int o = 32; o; o >>= 1) v = fmaxf(v, __shfl_xor(v, o));
  return v;
}
DEV_INLINE float wave_sum(float v) {
#pragma unroll
  for (int o = 32; o; o >>= 1) v += __shfl_xor(v, o);
  return v;
}

DEV_INLINE void gl_lds16(const u16* gp, char* lp) {
  __builtin_amdgcn_global_load_lds(
      (const __attribute__((address_space(1))) void*)gp,
      (__attribute__((address_space(3))) void*)lp, 16, 0, 0);
}

// XCD-bijective remap (m204)
DEV_INLINE void xcd_remap(int& bx, int& by) {
  const int gx = gridDim.x;
  const int nwg = gx * gridDim.y;
  const int id = blockIdx.x + gx * blockIdx.y;
  const int q = nwg >> 3, r = nwg & 7;
  const int x = id & 7, k = id >> 3;
  const int idp = (x < r) ? x * (q + 1) + k : r * (q + 1) + (x - r) * q + k;
  bx = idp % gx;
  by = idp / gx;
}

// =====================================================================
// fe1 GEMM, fp32 inputs read DIRECTLY (single-use data: converting first
// doubles traffic). Reg-staged: issue fp32 loads for step k+1 BEFORE the
// MFMAs (T14 issue-early/write-late), cvt+ds_write after, 1 barrier/step.
// blockIdx.x = K-chunk == XCD (R13-verified: FETCH 131->29MB); bn-fast
// tile order keeps the B K-slice L2-resident. split-K=8 partials.
// =====================================================================
__global__ __launch_bounds__(256) void gemm_fe1(
    const float* __restrict__ A, const float* __restrict__ Bw,
    float* __restrict__ outF)
{
  constexpr int lda = cDF, ldb = cDF, ldc = cREP;
  constexpr int Klen = cDF / 8;    // 1568
  __shared__ u16 As[2][128 * 32];
  __shared__ u16 Bs[2][128 * 32];
  const int tid = threadIdx.x;
  const int wid = tid >> 6, lane = tid & 63;
  const int l15 = lane & 15, l4 = lane >> 4;
  const int z = blockIdx.x;                 // K-chunk == XCD
  const int tile = blockIdx.y;              // 0..79
  const int bm = (tile >> 3) * 128;
  const int bn = (tile & 7) * 128;
  const int wr = wid >> 1, wc = wid & 1;
  const int kbase = z * Klen;

  // per-thread granule coords (2 granules per side)
  const int c0 = tid,        r0g = c0 >> 2, g0 = c0 & 3, s0 = g0 ^ (r0g & 3);
  const int c1 = 256 + tid,  r1g = c1 >> 2, g1 = c1 & 3, s1 = g1 ^ (r1g & 3);
  const float* a0p = A + (size_t)(bm + r0g) * lda + kbase + s0 * 8;
  const float* a1p = A + (size_t)(bm + r1g) * lda + kbase + s1 * 8;
  const float* b0p = Bw + (size_t)(bn + r0g) * ldb + kbase + s0 * 8;
  const float* b1p = Bw + (size_t)(bn + r1g) * ldb + kbase + s1 * 8;
  u16* a0d = &As[0][r0g * 32 + g0 * 8];
  u16* a1d = &As[0][r1g * 32 + g1 * 8];
  u16* b0d = &Bs[0][r0g * 32 + g0 * 8];
  u16* b1d = &Bs[0][r1g * 32 + g1 * 8];
  constexpr int BUFO = 128 * 32;   // u16 elems per buffer

  f32x4 acc[4][4] = {};

  float4 va0, va1, va2, va3, vb0, vb1, vb2, vb3;
  auto loadRegs = [&](int ks) {
    const int k = ks << 5;
    const float4* p;
    p = (const float4*)(a0p + k); va0 = p[0]; va1 = p[1];
    p = (const float4*)(a1p + k); va2 = p[0]; va3 = p[1];
    p = (const float4*)(b0p + k); vb0 = p[0]; vb1 = p[1];
    p = (const float4*)(b1p + k); vb2 = p[0]; vb3 = p[1];
  };
  auto writeLds = [&](int buf) {
    const int o = buf * BUFO;
    *(bf8_t*)(a0d + o) = cvt8(va0, va1);
    *(bf8_t*)(a1d + o) = cvt8(va2, va3);
    *(bf8_t*)(b0d + o) = cvt8(vb0, vb1);
    *(bf8_t*)(b1d + o) = cvt8(vb2, vb3);
  };

  const int nk = Klen >> 5;   // 49
  loadRegs(0);
  writeLds(0);
  __syncthreads();

  for (int ks = 0; ks < nk; ++ks) {
    const int cur = ks & 1;
    if (ks + 1 < nk) loadRegs(ks + 1);   // issue early; waits land at writeLds

    bf8_t af[4], bfr[4];
#pragma unroll
    for (int m = 0; m < 4; ++m) {
      const int r = wr * 64 + m * 16 + l15;
      const int g = l4 ^ (r & 3);
      af[m] = *(const bf8_t*)&As[cur][r * 32 + g * 8];
    }
#pragma unroll
    for (int n = 0; n < 4; ++n) {
      const int r = wc * 64 + n * 16 + l15;
      const int g = l4 ^ (r & 3);
      bfr[n] = *(const bf8_t*)&Bs[cur][r * 32 + g * 8];
    }
#pragma unroll
    for (int m = 0; m < 4; ++m)
#pragma unroll
      for (int n = 0; n < 4; ++n)
        acc[m][n] = __builtin_amdgcn_mfma_f32_16x16x32_bf16(af[m], bfr[n], acc[m][n], 0, 0, 0);

    if (ks + 1 < nk) writeLds(cur ^ 1);  // cvt + ds_write after MFMAs
    __syncthreads();
  }

  float* po = outF + (size_t)z * cN * ldc;
#pragma unroll
  for (int m = 0; m < 4; ++m)
#pragma unroll
    for (int n = 0; n < 4; ++n) {
      const int ccol = bn + wc * 64 + n * 16 + l15;
#pragma unroll
      for (int g = 0; g < 4; ++g) {
        const int r = bm + wr * 64 + m * 16 + l4 * 4 + g;
        po[(size_t)r * ldc + ccol] = acc[m][n][g];
      }
    }
}

// =====================================================================
// bf16 MFMA GEMM (general K): dbuf BK=32 (R6 proven)
// =====================================================================
template <int BM, int BN, bool SPLIT>
__global__ __launch_bounds__(256) void gemm_h(
    const u16* __restrict__ A, int lda,
    const u16* __restrict__ Bw, int ldb,
    int Mr, int Nr, int Klen,
    float* __restrict__ outF, int ldc,
    u16* __restrict__ outH, int ldh,
    const float* __restrict__ bias,
    const float* __restrict__ res, int resld, int resmode,
    int relu)
{
  constexpr int MF = BM > 32 ? BM / 32 : 1, NF = BN > 32 ? BN / 32 : 1;
  constexpr int ACH = BM * 4, BCH = BN * 4;
  __shared__ u16 As[2][BM * 32];
  __shared__ u16 Bs[2][BN * 32];
  const int tid = threadIdx.x;
  const int wid = tid >> 6, lane = tid & 63;
  const int l15 = lane & 15, l4 = lane >> 4;
  int bx, by;
  xcd_remap(bx, by);
  const int bm = by * BM, bn = bx * BN;
  const int wr = wid >> 1, wc = wid & 1;
  const int kbase = SPLIT ? blockIdx.z * Klen : 0;

  f32x4 acc[MF][NF] = {};

  auto stage = [&](int buf, int ks) {
    const int k0 = kbase + (ks << 5);
#pragma unroll
    for (int i = 0; i < (ACH + 255) / 256; ++i) {
      const int cA = i * 256 + tid;
      if (ACH % 256 == 0 || cA < ACH) {
        const int row = cA >> 2, seg = cA & 3;
        const int sseg = seg ^ (row & 3);
        gl_lds16(A + (size_t)(bm + row) * lda + k0 + sseg * 8,
                 (char*)As[buf] + (size_t)(cA - lane) * 16);
      }
    }
#pragma unroll
    for (int i = 0; i < (BCH + 255) / 256; ++i) {
      const int cBp = i * 256 + ((tid + 128) & 255);
      if (BCH % 256 == 0 || cBp < BCH) {
        const int row = cBp >> 2, seg = cBp & 3;
        const int sseg = seg ^ (row & 3);
        int brow = bn + row; if (brow > Nr - 1) brow = Nr - 1;
        gl_lds16(Bw + (size_t)brow * ldb + k0 + sseg * 8,
                 (char*)Bs[buf] + (size_t)(cBp - lane) * 16);
      }
    }
  };

  const int nk = Klen >> 5;
  stage(0, 0);
  __syncthreads();

  for (int ks = 0; ks < nk; ++ks) {
    const int cur = ks & 1;
    if (ks + 1 < nk) stage(cur ^ 1, ks + 1);

    bf8_t af[MF], bfr[NF];
#pragma unroll
    for (int m = 0; m < MF; ++m) {
      const int r = wr * (BM / 2) + m * 16 + l15;
      const int g = l4 ^ (r & 3);
      af[m] = *(const bf8_t*)&As[cur][r * 32 + g * 8];
    }
#pragma unroll
    for (int n = 0; n < NF; ++n) {
      const int r = wc * (BN / 2) + n * 16 + l15;
      const int g = l4 ^ (r & 3);
      bfr[n] = *(const bf8_t*)&Bs[cur][r * 32 + g * 8];
    }
#pragma unroll
    for (int m = 0; m < MF; ++m)
#pragma unroll
      for (int n = 0; n < NF; ++n)
        acc[m][n] = __builtin_amdgcn_mfma_f32_16x16x32_bf16(af[m], bfr[n], acc[m][n], 0, 0, 0);
    __syncthreads();
  }

  if (SPLIT) {
    float* po = outF + (size_t)blockIdx.z * Mr * ldc;
#pragma unroll
    for (int m = 0; m < MF; ++m)
#pragma unroll
      for (int n = 0; n < NF; ++n) {
        const int ccol = bn + wc * (BN / 2) + n * 16 + l15;
        if (ccol >= Nr) continue;
#pragma unroll
        for (int g = 0; g < 4; ++g) {
          const int r = bm + wr * (BM / 2) + m * 16 + l4 * 4 + g;
          po[(size_t)r * ldc + ccol] = acc[m][n][g];
        }
      }
  } else {
#pragma unroll
    for (int m = 0; m < MF; ++m)
#pragma unroll
      for (int n = 0; n < NF; ++n) {
        const int ccol = bn + wc * (BN / 2) + n * 16 + l15;
        if (ccol >= Nr) continue;
        const float bv = bias ? bias[ccol] : 0.f;
#pragma unroll
        for (int g = 0; g < 4; ++g) {
          const int r = bm + wr * (BM / 2) + m * 16 + l4 * 4 + g;
          float v = acc[m][n][g] + bv;
          if (resmode == 1) v += res[(size_t)r * resld + ccol];
          else if (resmode == 2) v += res[(size_t)(r >> 8) * resld + ccol];
          if (relu) v = fmaxf(v, 0.f);
          if (outF) outF[(size_t)r * ldc + ccol] = v;
          if (outH) outH[(size_t)r * ldh + ccol] = f2bf(v);
        }
      }
  }
}

template <int BM, int BN>
static void g16(hipStream_t s, const u16* A, int lda, const u16* W, int ldb,
                int M, int N, int K, float* outF, int ldc, u16* outH, int ldh,
                const float* bias, const float* res, int resld, int resmode, int relu) {
  dim3 g((N + BN - 1) / BN, M / BM);
  gemm_h<BM, BN, false><<<g, 256, 0, s>>>(A, lda, W, ldb, M, N, K, outF, ldc, outH, ldh,
                                          bias, res, resld, resmode, relu);
}

// ---------- converts: encoder/final weights only (multi-kernel bf16 users) ----------
constexpr size_t W_FE2 = 0, W_LOBJ = W_FE2 + 1048576, W_LEDGE = W_LOBJ + 720896,
  W_OQKV = W_LEDGE + 393216, W_OOUT = W_OQKV + 3145728, W_OF1 = W_OOUT + 1048576,
  W_OF2 = W_OF1 + 1048576, W_EQKV = W_OF2 + 1048576, W_EOUT = W_EQKV + 3145728,
  W_EF1 = W_EOUT + 1048576, W_EF2 = W_EF1 + 1048576, W_PCAT = W_EF2 + 1048576,
  W_FUSE = W_PCAT + 1048576, W_WEND = W_FUSE + 1572864;   // 16,580,608 u16

struct EncSrcs {
  const float *fe2, *lobj, *ledge, *oqkv, *oout, *of1, *of2,
              *eqkv, *eout, *ef1, *ef2, *pcat, *fuse;
};

__global__ void conv_enc(EncSrcs S, u16* __restrict__ wb) {
#define SEG(nm, OFF, PRE, LEN) \
  if (i < (PRE) + (LEN)) { \
    const float4 v = ((const float4*)S.nm)[i - (PRE)]; \
    ushort4 o = {f2bf(v.x), f2bf(v.y), f2bf(v.z), f2bf(v.w)}; \
    ((ushort4*)(wb + (OFF)))[i - (PRE)] = o; \
  } else
  for (int i = blockIdx.x * 256 + threadIdx.x; i < (int)(W_WEND / 4); i += gridDim.x * 256) {
    SEG(fe2,  W_FE2,   0,       262144)
    SEG(lobj, W_LOBJ,  262144,  180224)
    SEG(ledge,W_LEDGE, 442368,  98304)
    SEG(oqkv, W_OQKV,  540672,  786432)
    SEG(oout, W_OOUT,  1327104, 262144)
    SEG(of1,  W_OF1,   1589248, 262144)
    SEG(of2,  W_OF2,   1851392, 262144)
    SEG(eqkv, W_EQKV,  2113536, 786432)
    SEG(eout, W_EOUT,  2899968, 262144)
    SEG(ef1,  W_EF1,   3162112, 262144)
    SEG(ef2,  W_EF2,   3424256, 262144)
    SEG(pcat, W_PCAT,  3686400, 262144)
    SEG(fuse, W_FUSE,  3948544, 393216)
    { }
  }
#undef SEG
}

__global__ void conv_cat(const float* __restrict__ cpx, const float* __restrict__ dpath,
                         const float* __restrict__ cb, const float* __restrict__ db,
                         u16* __restrict__ catw, float* __restrict__ biasc) {
  constexpr int N1 = cRELC * 512;
  constexpr int N2 = cRELC * 256;
  const int i0 = blockIdx.x * 256 + threadIdx.x;
  if (blockIdx.x == 0 && threadIdx.x < cRELC) biasc[threadIdx.x] = cb[threadIdx.x] + db[threadIdx.x];
  for (int i = i0; i < N1 + N2; i += gridDim.x * 256) {
    if (i < N1) {
      const int r = i >> 9, c = i & 511;
      const float4 v = ((const float4*)cpx)[i];
      ushort4 o = {f2bf(v.x), f2bf(v.y), f2bf(v.z), f2bf(v.w)};
      ((ushort4*)catw)[r * 768 + c] = o;
    } else {
      const int j = i - N1, r = j >> 8, c = j & 255;
      const float4 v = ((const float4*)dpath)[j];
      ushort4 o = {f2bf(v.x), f2bf(v.y), f2bf(v.z), f2bf(v.w)};
      ((ushort4*)catw)[r * 768 + 512 + c] = o;
    }
  }
}

__global__ void conv2d_kernel(const float* __restrict__ src, int slda,
                              u16* __restrict__ dst, int dld, int cols) {
  const int r = blockIdx.x;
  for (int c = threadIdx.x; c < cols; c += blockDim.x)
    dst[(size_t)r * dld + c] = f2bf(src[(size_t)r * slda + c]);
}

// ---------- fused box geometry + pos MLP + emb1 gather ----------
__global__ __launch_bounds__(256) void prep_obj(
    const float* __restrict__ boxes,
    const float* __restrict__ bb1w, const float* __restrict__ bb1b,
    const float* __restrict__ bb2w, const float* __restrict__ bb2b,
    const float* __restrict__ emb1, const int* __restrict__ labels,
    u16* __restrict__ obj_in) {
  __shared__ float W1[288];
  __shared__ float W2[4096];
  __shared__ float P1[8][33];
  const int tid = threadIdx.x;
  for (int i = tid; i < 288; i += 256) W1[i] = bb1w[i];
  for (int i = tid; i < 4096; i += 256) W2[i] = bb2w[i];
  __syncthreads();
  const int r8 = tid >> 5, sub = tid & 31;
  const int row = blockIdx.x * 8 + r8;
  const float x1 = boxes[row * 4], y1 = boxes[row * 4 + 1];
  const float x2 = boxes[row * 4 + 2], y2 = boxes[row * 4 + 3];
  const float w = x2 - x1 + 1.f, h = y2 - y1 + 1.f;
  const float bi[9] = {w / 800.f, h / 600.f, (x1 + 0.5f * w) / 800.f, (y1 + 0.5f * h) / 600.f,
                       x1 / 800.f, y1 / 600.f, x2 / 800.f, y2 / 600.f, w * h / 480000.f};
  float p = bb1b[sub];
#pragma unroll
  for (int j = 0; j < 9; ++j) p += bi[j] * W1[sub * 9 + j];
  P1[r8][sub] = fmaxf(p, 0.f);
  __syncthreads();
#pragma unroll
  for (int jo = 0; jo < 4; ++jo) {
    const int o = sub + jo * 32;
    float a = bb2b[o];
#pragma unroll
    for (int j2 = 0; j2 < 32; ++j2) a += P1[r8][j2] * W2[o * 32 + j2];
    obj_in[(size_t)row * 1408 + 1280 + o] = f2bf(fmaxf(a, 0.f));
  }
  const int l = labels[row];
#pragma unroll
  for (int k = 0; k < 8; ++k)
    obj_in[(size_t)row * 1408 + 1024 + sub + k * 32] = f2bf(emb1[(size_t)l * 256 + sub + k * 32]);
}

// ---------- merged emb2 gather + pair gather ----------
__global__ void gather_pair(const float* __restrict__ emb2, const int* __restrict__ labels,
                            u16* __restrict__ edge_in,               // [1280][768]
                            const int* __restrict__ idx, u16* __restrict__ pair) {
  const int r = blockIdx.x;
  const int tid = threadIdx.x;
  if (r < cN) {
    const int l = labels[r];
    edge_in[(size_t)r * 768 + 512 + tid] = f2bf(emb2[(size_t)l * cEMB + tid]);
  }
  const int b = r >> 8, rr = r & 255;
  const int i0 = idx[(size_t)(b * cRPI + rr) * 2 + 0];
  const int i1 = idx[(size_t)(b * cRPI + rr) * 2 + 1];
  const u16* hsrc = edge_in + (size_t)(b * cM + i0) * 768;
  const u16* tsrc = edge_in + (size_t)(b * cM + i1) * 768;
  u16* p = pair + (size_t)r * 1024;
  for (int c = tid; c < cHID; c += blockDim.x) {
    p[c] = hsrc[c];
    p[cHID + c] = tsrc[c];
  }
}

// fused attention per (b,h): qkv bf16 in, bf16 out (vectorized K/V fill)
__global__ __launch_bounds__(256) void attn_kernel(const u16* __restrict__ qkv,
                                                   u16* __restrict__ o) {
  __shared__ float Ks[80][65];
  __shared__ float Vs[80][65];
  const int bh = blockIdx.x;
  const int b = bh >> 3, h = bh & 7;
  const int tid = threadIdx.x;
  const u16* base = qkv + (size_t)(b * cM) * 1536 + h * 64;

  for (int e = tid; e < 640; e += 256) {
    const int r = e >> 3, d0 = (e & 7) * 8;
    const bf8_t kv = *(const bf8_t*)&base[(size_t)r * 1536 + 512 + d0];
    const bf8_t vv = *(const bf8_t*)&base[(size_t)r * 1536 + 1024 + d0];
#pragma unroll
    for (int j = 0; j < 8; ++j) {
      Ks[r][d0 + j] = bf2f((u16)kv[j]);
      Vs[r][d0 + j] = bf2f((u16)vv[j]);
    }
  }
  __syncthreads();

  const int wave = tid >> 6, lane = tid & 63;
  const int r0 = blockIdx.y * 16;
  for (int r = r0 + wave; r < r0 + 16; r += 4) {
    const float qd = bf2f(base[(size_t)r * 1536 + lane]);
    const int c2 = 64 + lane;
    const int c2c = (c2 < 80) ? c2 : 0;
    float s0 = 0.f, s1 = 0.f;
#pragma unroll 8
    for (int d = 0; d < 64; ++d) {
      const float qv = __shfl(qd, d);
      s0 += qv * Ks[lane][d];
      s1 += qv * Ks[c2c][d];
    }
    s0 *= 0.125f;
    s1 = (c2 < 80) ? s1 * 0.125f : -1e30f;
    const float mx = wave_max(fmaxf(s0, s1));
    const float p0 = __expf(s0 - mx);
    const float p1 = (c2 < 80) ? __expf(s1 - mx) : 0.f;
    const float ssum = wave_sum(p0 + p1);

    float od = 0.f;
#pragma unroll 8
    for (int c = 0; c < 64; ++c) od += __shfl(p0, c) * Vs[c][lane];
#pragma unroll
    for (int c = 0; c < 16; ++c) od += __shfl(p1, c) * Vs[64 + c][lane];
    od /= ssum;
    o[(size_t)(b * cM + r) * cHID + h * 64 + lane] = f2bf(od);
  }
}

// LayerNorm: 4 rows/block, 1 wave/row, fp32 out + bf16 mirror
__global__ __launch_bounds__(256) void ln_kernel(
    const float* __restrict__ in, float* __restrict__ outF,
    u16* __restrict__ outH, int ldh,
    const float* __restrict__ g, const float* __restrict__ bta) {
  const int row = blockIdx.x * 4 + (threadIdx.x >> 6);
  const int lane = threadIdx.x & 63;
  const float* x = in + (size_t)row * cHID;
  float v[8];
  float s = 0.f;
#pragma unroll
  for (int i = 0; i < 8; ++i) { v[i] = x[lane + i * 64]; s += v[i]; }
  s = wave_sum(s);
  const float mean = s * (1.f / 512.f);
  float vs = 0.f;
#pragma unroll
  for (int i = 0; i < 8; ++i) { const float d = v[i] - mean; vs += d * d; }
  vs = wave_sum(vs);
  const float inv = rsqrtf(vs * (1.f / 512.f) + 1e-5f);
#pragma unroll
  for (int i = 0; i < 8; ++i) {
    const int c = lane + i * 64;
    const float y = (v[i] - mean) * inv * g[c] + bta[c];
    outF[(size_t)row * cHID + c] = y;
    outH[(size_t)row * ldh + c] = f2bf(y);
  }
}

__global__ void mean_kernel(const float* __restrict__ x, u16* __restrict__ gctx_h) {
  const int b = blockIdx.x;
  const int c = threadIdx.x;  // 512
  float s = 0.f;
  for (int m = 0; m < cM; ++m) s += x[(size_t)(b * cM + m) * cHID + c];
  gctx_h[(size_t)b * cHID + c] = f2bf(s * (1.f / 80.f));
}

__global__ void reduce8_kernel(const float* __restrict__ p, const float* __restrict__ bias,
                               u16* __restrict__ outH) {
  const int idx = blockIdx.x * 256 + threadIdx.x;
  constexpr int total = cN * cREP;
  if (idx >= total) return;
  float v = bias[idx & 1023];
#pragma unroll
  for (int z = 0; z < 8; ++z) v += p[(size_t)z * total + idx];
  outH[idx] = f2bf(fmaxf(v, 0.f));
}

__global__ void freduce_kernel(const float* __restrict__ p, const float* __restrict__ biasc,
                               float* __restrict__ out) {
  const int idx = blockIdx.x * 256 + threadIdx.x;
  if (idx >= cR * cRELC) return;
  const int r = idx / cRELC, c = idx - r * cRELC;
  float v = biasc[c];
#pragma unroll
  for (int z = 0; z < 4; ++z) v += p[(size_t)z * cR * 64 + (size_t)r * 64 + c];
  out[idx] = v;
}

// ---------- encoder: 7 dispatches per layer, 32x32 GEMM tiles (R6 proven) ----------
static void run_encoder(hipStream_t s, float* x, u16* xh, u16* qkvh, u16* attn_h,
                        float* res1, u16* f_h,
                        const u16* qkvw, const float* qkvb,
                        const u16* outw, const float* outb,
                        const u16* f1w, const float* f1b,
                        const u16* f2w, const float* f2b,
                        const float* ln1s, const float* ln1b,
                        const float* ln2s, const float* ln2b,
                        u16* last_bf, int last_ld) {
  for (int l = 0; l < cL; ++l) {
    g16<32, 32>(s, xh, 512, qkvw + (size_t)l * 1536 * 512, 512, cN, 1536, 512,
                nullptr, 0, qkvh, 1536, qkvb + l * 1536, nullptr, 0, 0, 0);
    attn_kernel<<<dim3(cB * cNH, 5), 256, 0, s>>>(qkvh, attn_h);
    g16<32, 32>(s, attn_h, 512, outw + (size_t)l * 512 * 512, 512, cN, 512, 512,
                res1, 512, nullptr, 0, outb + l * 512, x, 512, 1, 0);
    ln_kernel<<<cN / 4, 256, 0, s>>>(res1, x, xh, 512, ln1s + l * 512, ln1b + l * 512);
    g16<32, 32>(s, xh, 512, f1w + (size_t)l * 512 * 512, 512, cN, 512, 512,
                nullptr, 0, f_h, 512, f1b + l * 512, nullptr, 0, 0, 1);
    g16<32, 32>(s, f_h, 512, f2w + (size_t)l * 512 * 512, 512, cN, 512, 512,
                res1, 512, nullptr, 0, f2b + l * 512, x, 512, 1, 0);
    const bool last = (l == cL - 1);
    ln_kernel<<<cN / 4, 256, 0, s>>>(res1, x, last ? last_bf : xh, last ? last_ld : 512,
                                     ln2s + l * 512, ln2b + l * 512);
  }
}

// ===== workspace layout (bytes) =====
constexpr size_t OFF_PART  = 57802752;   // 8*1280*1024*4
constexpr size_t P_END     = 99745792;
constexpr size_t OFF_PAIR  = 0;
constexpr size_t OFF_FINAL = 8388608;
constexpr size_t OFF_OBJIN = 33554432;
constexpr size_t OFF_QKVH  = 37158912;
constexpr size_t OFF_X     = 41091072;
constexpr size_t OFF_XH    = 43712512;
constexpr size_t OFF_ATTN  = 45023232;
constexpr size_t OFF_RES   = 46333952;
constexpr size_t OFF_FH    = 48955392;
constexpr size_t OFF_EDGE  = 50266112;   // ends 52,232,192

extern "C" void kernel_launch(void* const* d_in, const int* in_sizes, int n_in,
                              void* d_out, int out_size, void* d_ws, size_t ws_size,
                              hipStream_t stream) {
  (void)in_sizes; (void)n_in; (void)out_size; (void)ws_size;

  const float* features = (const float*)d_in[0];
  const float* unionf   = (const float*)d_in[1];
  const float* boxes    = (const float*)d_in[2];
  const int*   labels   = (const int*)d_in[4];
  const int*   relidx   = (const int*)d_in[5];
  const float* fe1_w = (const float*)d_in[6];
  const float* fe1_b = (const float*)d_in[7];
  const float* fe2_w = (const float*)d_in[8];
  const float* fe2_b = (const float*)d_in[9];
  const float* emb1  = (const float*)d_in[10];
  const float* emb2  = (const float*)d_in[11];
  const float* bb1_w = (const float*)d_in[12];
  const float* bb1_b = (const float*)d_in[13];
  const float* bb2_w = (const float*)d_in[14];
  const float* bb2_b = (const float*)d_in[15];
  const float* lobj_w = (const float*)d_in[16];
  const float* lobj_b = (const float*)d_in[17];
  const float* ledge_w = (const float*)d_in[18];
  const float* ledge_b = (const float*)d_in[19];
  const float* oqkv_w = (const float*)d_in[20];
  const float* oqkv_b = (const float*)d_in[21];
  const float* oout_w = (const float*)d_in[22];
  const float* oout_b = (const float*)d_in[23];
  const float* of1_w = (const float*)d_in[24];
  const float* of1_b = (const float*)d_in[25];
  const float* of2_w = (const float*)d_in[26];
  const float* of2_b = (const float*)d_in[27];
  const float* oln1_s = (const float*)d_in[28];
  const float* oln1_b = (const float*)d_in[29];
  const float* oln2_s = (const float*)d_in[30];
  const float* oln2_b = (const float*)d_in[31];
  const float* eqkv_w = (const float*)d_in[32];
  const float* eqkv_b = (const float*)d_in[33];
  const float* eout_w = (const float*)d_in[34];
  const float* eout_b = (const float*)d_in[35];
  const float* ef1_w = (const float*)d_in[36];
  const float* ef1_b = (const float*)d_in[37];
  const float* ef2_w = (const float*)d_in[38];
  const float* ef2_b = (const float*)d_in[39];
  const float* eln1_s = (const float*)d_in[40];
  const float* eln1_b = (const float*)d_in[41];
  const float* eln2_s = (const float*)d_in[42];
  const float* eln2_b = (const float*)d_in[43];
  const float* pcat_w = (const float*)d_in[44];
  const float* pcat_b = (const float*)d_in[45];
  const float* fuse_w = (const float*)d_in[46];
  const float* fuse_b = (const float*)d_in[47];
  const float* cpx_w  = (const float*)d_in[48];
  const float* cpx_b  = (const float*)d_in[49];
  const float* dpath_w = (const float*)d_in[50];
  const float* dpath_b = (const float*)d_in[51];

  char* wsb = (char*)d_ws;
  float* part  = (float*)(wsb + OFF_PART);
  u16* pair    = (u16*)(wsb + OFF_PAIR);
  u16* finalb  = (u16*)(wsb + OFF_FINAL);
  u16* obj_in  = (u16*)(wsb + OFF_OBJIN);
  u16* qkvh    = (u16*)(wsb + OFF_QKVH);
  float* x     = (float*)(wsb + OFF_X);
  u16* xh      = (u16*)(wsb + OFF_XH);
  u16* attn_h  = (u16*)(wsb + OFF_ATTN);
  float* res1  = (float*)(wsb + OFF_RES);
  u16* f_h     = (u16*)(wsb + OFF_FH);
  u16* edge_in = (u16*)(wsb + OFF_EDGE);

  size_t off = P_END;
  auto alloc = [&](size_t bytes) { char* p = wsb + off; off = (off + bytes + 255) & ~(size_t)255; return p; };
  u16* wblock   = (u16*)alloc(W_WEND * 2);
  u16* catw     = (u16*)alloc(313344);
  float* biasc  = (float*)alloc(256);
  u16* bf0h     = (u16*)alloc(2621440);
  u16* gctx_h   = (u16*)alloc(65536);
  float* gcproj = (float*)alloc(262144);
  float* fpart  = (float*)alloc(4194304);

  const u16* fe2w_h   = wblock + W_FE2;
  const u16* lobjw_h  = wblock + W_LOBJ;
  const u16* ledgew_h = wblock + W_LEDGE;
  const u16* pcatw_h  = wblock + W_PCAT;
  const u16* fusew_h  = wblock + W_FUSE;

  // --- 1) fe1 split-K=8 DIRECT from fp32 (no feature/fe1_w converts) ---
  gemm_fe1<<<dim3(8, 80), 256, 0, stream>>>(features, fe1_w, part);
  reduce8_kernel<<<(cN * cREP + 255) / 256, 256, 0, stream>>>(part, fe1_b, bf0h);

  // --- 2) weight converts (multi-use bf16 consumers) ---
  EncSrcs es = {fe2_w, lobj_w, ledge_w, oqkv_w, oout_w, of1_w, of2_w,
                eqkv_w, eout_w, ef1_w, ef2_w, pcat_w, fuse_w};
  conv_enc<<<2048, 256, 0, stream>>>(es, wblock);
  conv_cat<<<160, 256, 0, stream>>>(cpx_w, dpath_w, cpx_b, dpath_b, catw, biasc);

  // --- 3) box path + emb1 gather ---
  prep_obj<<<cN / 8, 256, 0, stream>>>(boxes, bb1_w, bb1_b, bb2_w, bb2_b, emb1, labels, obj_in);

  // --- 4) fe2 -> obj_in[:, :1024] ---
  g16<32, 32>(stream, bf0h, 1024, fe2w_h, 1024, cN, cREP, cREP,
              nullptr, 0, obj_in, 1408, fe2_b, nullptr, 0, 0, 1);

  // --- 5) obj_rep -> x, xh ---
  g16<32, 32>(stream, obj_in, 1408, lobjw_h, 1408, cN, cHID, 1408,
              x, 512, xh, 512, lobj_b, nullptr, 0, 0, 0);

  // --- 6) object encoder ---
  run_encoder(stream, x, xh, qkvh, attn_h, res1, f_h,
              wblock + W_OQKV, oqkv_b, wblock + W_OOUT, oout_b,
              wblock + W_OF1, of1_b, wblock + W_OF2, of2_b,
              oln1_s, oln1_b, oln2_s, oln2_b, edge_in, 768);

  // --- 7) emb2 gather + pair gather (merged) ---
  gather_pair<<<cR, 256, 0, stream>>>(emb2, labels, edge_in, relidx, pair);

  // --- 8) edge encoder ---
  g16<32, 32>(stream, edge_in, 768, ledgew_h, 768, cN, cHID, 768,
              x, 512, xh, 512, ledge_b, nullptr, 0, 0, 0);
  run_encoder(stream, x, xh, qkvh, attn_h, res1, f_h,
              wblock + W_EQKV, eqkv_b, wblock + W_EOUT, eout_b,
              wblock + W_EF1, ef1_b, wblock + W_EF2, ef2_b,
              eln1_s, eln1_b, eln2_s, eln2_b, xh, 512);
  mean_kernel<<<cB, cHID, 0, stream>>>(x, gctx_h);

  // --- 9) gcproj = gctx @ fuse_w[:,1024:]^T + fuse_b ---
  g16<32, 64>(stream, gctx_h, 512, fusew_h + 1024, 1536, 64, cREP, 512,
              gcproj, 1024, nullptr, 0, fuse_b, nullptr, 0, 0, 0);

  // --- 10) final feature block ---
  conv2d_kernel<<<cR, 256, 0, stream>>>(unionf, 1024, finalb + 1024, 3072, 1024);
  g16<128, 64>(stream, pair, 1024, pcatw_h, 1024, cR, cREP, 1024,
               nullptr, 0, finalb + 2048, 3072, pcat_b, nullptr, 0, 0, 0);
  g16<128, 64>(stream, finalb + 2048, 3072, fusew_h, 1536, cR, cREP, 1024,
               nullptr, 0, finalb, 3072, nullptr, gcproj, 1024, 2, 1);

  // --- 11) rel_logits ---
  gemm_h<64, 64, true><<<dim3(1, 64, 4), 256, 0, stream>>>(
      finalb, 3072, catw, 3072, cR, cRELC, 3072 / 4, fpart, 64,
      nullptr, 0, nullptr, nullptr, 0, 0, 0);
  freduce_kernel<<<(cR * cRELC + 255) / 256, 256, 0, stream>>>(fpart, biasc, (float*)d_out);
}

// Round 15
// 881.017 us; speedup vs baseline: 1.0056x; 1.0056x over previous
//
#include <hip/hip_runtime.h>
#include <hip/hip_bf16.h>
#include <cstdint>

#define DEV_INLINE __device__ __forceinline__

using u16 = unsigned short;
typedef __attribute__((ext_vector_type(8))) short bf8_t;   // 8 x bf16 (4 VGPR)
typedef __attribute__((ext_vector_type(4))) float f32x4;

constexpr int cB = 16, cM = 80, cRPI = 256;
constexpr int cN = cB * cM;        // 1280
constexpr int cR = cB * cRPI;      // 4096
constexpr int cDF = 12544, cREP = 1024, cEMB = 256, cHID = 512, cNH = 8, cL = 4;
constexpr int cRELC = 51;

DEV_INLINE u16 f2bf(float x) { return __builtin_bit_cast(u16, __float2bfloat16(x)); }
DEV_INLINE float bf2f(u16 u) { return __bfloat162float(__builtin_bit_cast(__hip_bfloat16, u)); }

DEV_INLINE float wave_max(float v) {
#pragma unroll
  for (int o = 32; o; o >>= 1) v = fmaxf(v, __shfl_xor(v, o));
  return v;
}
DEV_INLINE float wave_sum(float v) {
#pragma unroll
  for (int o = 32; o; o >>= 1) v += __shfl_xor(v, o);
  return v;
}

DEV_INLINE void gl_lds16(const u16* gp, char* lp) {
  __builtin_amdgcn_global_load_lds(
      (const __attribute__((address_space(1))) void*)gp,
      (__attribute__((address_space(3))) void*)lp, 16, 0, 0);
}

// XCD-bijective remap (m204)
DEV_INLINE void xcd_remap(int& bx, int& by) {
  const int gx = gridDim.x;
  const int nwg = gx * gridDim.y;
  const int id = blockIdx.x + gx * blockIdx.y;
  const int q = nwg >> 3, r = nwg & 7;
  const int x = id & 7, k = id >> 3;
  const int idp = (x < r) ? x * (q + 1) + k : r * (q + 1) + (x - r) * q + k;
  bx = idp % gx;
  by = idp / gx;
}

// =====================================================================
// fe1 GEMM: bf16 inputs, split-K=8, K-chunk == XCD (R13-verified:
// FETCH 131->29MB). Retiled 64x128 (grid 8x160 = 1280 blocks -> 5/CU
// co-residency vs R13's 2.5; LDS 24KB). bn-fast keeps B K-slice
// L2-resident; A panel (200KB) reused across its 8 col tiles.
// =====================================================================
__global__ __launch_bounds__(256) void gemm_fe1(
    const u16* __restrict__ A, const u16* __restrict__ Bw,
    float* __restrict__ outF)
{
  constexpr int lda = cDF, ldb = cDF, ldc = cREP;
  constexpr int Klen = cDF / 8;    // 1568
  __shared__ u16 As[2][64 * 32];
  __shared__ u16 Bs[2][128 * 32];
  const int tid = threadIdx.x;
  const int wid = tid >> 6, lane = tid & 63;
  const int l15 = lane & 15, l4 = lane >> 4;
  const int z = blockIdx.x;                 // K-chunk == XCD
  const int tile = blockIdx.y;              // 0..159
  const int bm = (tile >> 3) * 64;          // 20 row panels (slow)
  const int bn = (tile & 7) * 128;          // 8 col panels (fast)
  const int wr = wid >> 1, wc = wid & 1;
  const int kbase = z * Klen;

  f32x4 acc[2][4] = {};

  auto stage = [&](int buf, int ks) {
    const int k0 = kbase + (ks << 5);
    {
      const int cA = tid;                   // 256 chunks (64 rows x 4)
      const int row = cA >> 2, seg = cA & 3;
      const int sseg = seg ^ (row & 3);
      gl_lds16(A + (size_t)(bm + row) * lda + k0 + sseg * 8,
               (char*)As[buf] + (size_t)(cA - lane) * 16);
    }
#pragma unroll
    for (int i = 0; i < 2; ++i) {
      const int cB2 = i * 256 + tid;        // 512 chunks (128 rows x 4)
      const int row = cB2 >> 2, seg = cB2 & 3;
      const int sseg = seg ^ (row & 3);
      gl_lds16(Bw + (size_t)(bn + row) * ldb + k0 + sseg * 8,
               (char*)Bs[buf] + (size_t)(cB2 - lane) * 16);
    }
  };

  const int nk = Klen >> 5;   // 49
  stage(0, 0);
  __syncthreads();

  for (int ks = 0; ks < nk; ++ks) {
    const int cur = ks & 1;
    if (ks + 1 < nk) stage(cur ^ 1, ks + 1);

    bf8_t af[2], bfr[4];
#pragma unroll
    for (int m = 0; m < 2; ++m) {
      const int r = wr * 32 + m * 16 + l15;
      const int g = l4 ^ (r & 3);
      af[m] = *(const bf8_t*)&As[cur][r * 32 + g * 8];
    }
#pragma unroll
    for (int n = 0; n < 4; ++n) {
      const int r = wc * 64 + n * 16 + l15;
      const int g = l4 ^ (r & 3);
      bfr[n] = *(const bf8_t*)&Bs[cur][r * 32 + g * 8];
    }
#pragma unroll
    for (int m = 0; m < 2; ++m)
#pragma unroll
      for (int n = 0; n < 4; ++n)
        acc[m][n] = __builtin_amdgcn_mfma_f32_16x16x32_bf16(af[m], bfr[n], acc[m][n], 0, 0, 0);
    __syncthreads();
  }

  float* po = outF + (size_t)z * cN * ldc;
#pragma unroll
  for (int m = 0; m < 2; ++m)
#pragma unroll
    for (int n = 0; n < 4; ++n) {
      const int ccol = bn + wc * 64 + n * 16 + l15;
#pragma unroll
      for (int g = 0; g < 4; ++g) {
        const int r = bm + wr * 32 + m * 16 + l4 * 4 + g;
        po[(size_t)r * ldc + ccol] = acc[m][n][g];
      }
    }
}

// =====================================================================
// bf16 MFMA GEMM (general K): dbuf BK=32 (R6 proven)
// =====================================================================
template <int BM, int BN, bool SPLIT>
__global__ __launch_bounds__(256) void gemm_h(
    const u16* __restrict__ A, int lda,
    const u16* __restrict__ Bw, int ldb,
    int Mr, int Nr, int Klen,
    float* __restrict__ outF, int ldc,
    u16* __restrict__ outH, int ldh,
    const float* __restrict__ bias,
    const float* __restrict__ res, int resld, int resmode,
    int relu)
{
  constexpr int MF = BM > 32 ? BM / 32 : 1, NF = BN > 32 ? BN / 32 : 1;
  constexpr int ACH = BM * 4, BCH = BN * 4;
  __shared__ u16 As[2][BM * 32];
  __shared__ u16 Bs[2][BN * 32];
  const int tid = threadIdx.x;
  const int wid = tid >> 6, lane = tid & 63;
  const int l15 = lane & 15, l4 = lane >> 4;
  int bx, by;
  xcd_remap(bx, by);
  const int bm = by * BM, bn = bx * BN;
  const int wr = wid >> 1, wc = wid & 1;
  const int kbase = SPLIT ? blockIdx.z * Klen : 0;

  f32x4 acc[MF][NF] = {};

  auto stage = [&](int buf, int ks) {
    const int k0 = kbase + (ks << 5);
#pragma unroll
    for (int i = 0; i < (ACH + 255) / 256; ++i) {
      const int cA = i * 256 + tid;
      if (ACH % 256 == 0 || cA < ACH) {
        const int row = cA >> 2, seg = cA & 3;
        const int sseg = seg ^ (row & 3);
        gl_lds16(A + (size_t)(bm + row) * lda + k0 + sseg * 8,
                 (char*)As[buf] + (size_t)(cA - lane) * 16);
      }
    }
#pragma unroll
    for (int i = 0; i < (BCH + 255) / 256; ++i) {
      const int cBp = i * 256 + ((tid + 128) & 255);
      if (BCH % 256 == 0 || cBp < BCH) {
        const int row = cBp >> 2, seg = cBp & 3;
        const int sseg = seg ^ (row & 3);
        int brow = bn + row; if (brow > Nr - 1) brow = Nr - 1;
        gl_lds16(Bw + (size_t)brow * ldb + k0 + sseg * 8,
                 (char*)Bs[buf] + (size_t)(cBp - lane) * 16);
      }
    }
  };

  const int nk = Klen >> 5;
  stage(0, 0);
  __syncthreads();

  for (int ks = 0; ks < nk; ++ks) {
    const int cur = ks & 1;
    if (ks + 1 < nk) stage(cur ^ 1, ks + 1);

    bf8_t af[MF], bfr[NF];
#pragma unroll
    for (int m = 0; m < MF; ++m) {
      const int r = wr * (BM / 2) + m * 16 + l15;
      const int g = l4 ^ (r & 3);
      af[m] = *(const bf8_t*)&As[cur][r * 32 + g * 8];
    }
#pragma unroll
    for (int n = 0; n < NF; ++n) {
      const int r = wc * (BN / 2) + n * 16 + l15;
      const int g = l4 ^ (r & 3);
      bfr[n] = *(const bf8_t*)&Bs[cur][r * 32 + g * 8];
    }
#pragma unroll
    for (int m = 0; m < MF; ++m)
#pragma unroll
      for (int n = 0; n < NF; ++n)
        acc[m][n] = __builtin_amdgcn_mfma_f32_16x16x32_bf16(af[m], bfr[n], acc[m][n], 0, 0, 0);
    __syncthreads();
  }

  if (SPLIT) {
    float* po = outF + (size_t)blockIdx.z * Mr * ldc;
#pragma unroll
    for (int m = 0; m < MF; ++m)
#pragma unroll
      for (int n = 0; n < NF; ++n) {
        const int ccol = bn + wc * (BN / 2) + n * 16 + l15;
        if (ccol >= Nr) continue;
#pragma unroll
        for (int g = 0; g < 4; ++g) {
          const int r = bm + wr * (BM / 2) + m * 16 + l4 * 4 + g;
          po[(size_t)r * ldc + ccol] = acc[m][n][g];
        }
      }
  } else {
#pragma unroll
    for (int m = 0; m < MF; ++m)
#pragma unroll
      for (int n = 0; n < NF; ++n) {
        const int ccol = bn + wc * (BN / 2) + n * 16 + l15;
        if (ccol >= Nr) continue;
        const float bv = bias ? bias[ccol] : 0.f;
#pragma unroll
        for (int g = 0; g < 4; ++g) {
          const int r = bm + wr * (BM / 2) + m * 16 + l4 * 4 + g;
          float v = acc[m][n][g] + bv;
          if (resmode == 1) v += res[(size_t)r * resld + ccol];
          else if (resmode == 2) v += res[(size_t)(r >> 8) * resld + ccol];
          if (relu) v = fmaxf(v, 0.f);
          if (outF) outF[(size_t)r * ldc + ccol] = v;
          if (outH) outH[(size_t)r * ldh + ccol] = f2bf(v);
        }
      }
  }
}

template <int BM, int BN>
static void g16(hipStream_t s, const u16* A, int lda, const u16* W, int ldb,
                int M, int N, int K, float* outF, int ldc, u16* outH, int ldh,
                const float* bias, const float* res, int resld, int resmode, int relu) {
  dim3 g((N + BN - 1) / BN, M / BM);
  gemm_h<BM, BN, false><<<g, 256, 0, s>>>(A, lda, W, ldb, M, N, K, outF, ldc, outH, ldh,
                                          bias, res, resld, resmode, relu);
}

// ---------- converts: 3 kernels (R6/R13 proven) ----------
__global__ void conv_big2(const float* __restrict__ f, const float* __restrict__ w,
                          u16* __restrict__ fh, u16* __restrict__ wh) {
  constexpr int N1 = cN * cDF / 4;
  constexpr int N2 = cREP * cDF / 4;
  for (int i = blockIdx.x * 256 + threadIdx.x; i < N1 + N2; i += gridDim.x * 256) {
    const float4 v = (i < N1) ? ((const float4*)f)[i] : ((const float4*)w)[i - N1];
    ushort4 o = {f2bf(v.x), f2bf(v.y), f2bf(v.z), f2bf(v.w)};
    if (i < N1) ((ushort4*)fh)[i] = o; else ((ushort4*)wh)[i - N1] = o;
  }
}

constexpr size_t W_FE2 = 0, W_LOBJ = W_FE2 + 1048576, W_LEDGE = W_LOBJ + 720896,
  W_OQKV = W_LEDGE + 393216, W_OOUT = W_OQKV + 3145728, W_OF1 = W_OOUT + 1048576,
  W_OF2 = W_OF1 + 1048576, W_EQKV = W_OF2 + 1048576, W_EOUT = W_EQKV + 3145728,
  W_EF1 = W_EOUT + 1048576, W_EF2 = W_EF1 + 1048576, W_PCAT = W_EF2 + 1048576,
  W_FUSE = W_PCAT + 1048576, W_WEND = W_FUSE + 1572864;   // 16,580,608 u16

struct EncSrcs {
  const float *fe2, *lobj, *ledge, *oqkv, *oout, *of1, *of2,
              *eqkv, *eout, *ef1, *ef2, *pcat, *fuse;
};

__global__ void conv_enc(EncSrcs S, u16* __restrict__ wb) {
#define SEG(nm, OFF, PRE, LEN) \
  if (i < (PRE) + (LEN)) { \
    const float4 v = ((const float4*)S.nm)[i - (PRE)]; \
    ushort4 o = {f2bf(v.x), f2bf(v.y), f2bf(v.z), f2bf(v.w)}; \
    ((ushort4*)(wb + (OFF)))[i - (PRE)] = o; \
  } else
  for (int i = blockIdx.x * 256 + threadIdx.x; i < (int)(W_WEND / 4); i += gridDim.x * 256) {
    SEG(fe2,  W_FE2,   0,       262144)
    SEG(lobj, W_LOBJ,  262144,  180224)
    SEG(ledge,W_LEDGE, 442368,  98304)
    SEG(oqkv, W_OQKV,  540672,  786432)
    SEG(oout, W_OOUT,  1327104, 262144)
    SEG(of1,  W_OF1,   1589248, 262144)
    SEG(of2,  W_OF2,   1851392, 262144)
    SEG(eqkv, W_EQKV,  2113536, 786432)
    SEG(eout, W_EOUT,  2899968, 262144)
    SEG(ef1,  W_EF1,   3162112, 262144)
    SEG(ef2,  W_EF2,   3424256, 262144)
    SEG(pcat, W_PCAT,  3686400, 262144)
    SEG(fuse, W_FUSE,  3948544, 393216)
    { }
  }
#undef SEG
}

__global__ void conv_cat(const float* __restrict__ cpx, const float* __restrict__ dpath,
                         const float* __restrict__ cb, const float* __restrict__ db,
                         u16* __restrict__ catw, float* __restrict__ biasc) {
  constexpr int N1 = cRELC * 512;
  constexpr int N2 = cRELC * 256;
  const int i0 = blockIdx.x * 256 + threadIdx.x;
  if (blockIdx.x == 0 && threadIdx.x < cRELC) biasc[threadIdx.x] = cb[threadIdx.x] + db[threadIdx.x];
  for (int i = i0; i < N1 + N2; i += gridDim.x * 256) {
    if (i < N1) {
      const int r = i >> 9, c = i & 511;
      const float4 v = ((const float4*)cpx)[i];
      ushort4 o = {f2bf(v.x), f2bf(v.y), f2bf(v.z), f2bf(v.w)};
      ((ushort4*)catw)[r * 768 + c] = o;
    } else {
      const int j = i - N1, r = j >> 8, c = j & 255;
      const float4 v = ((const float4*)dpath)[j];
      ushort4 o = {f2bf(v.x), f2bf(v.y), f2bf(v.z), f2bf(v.w)};
      ((ushort4*)catw)[r * 768 + 512 + c] = o;
    }
  }
}

__global__ void conv2d_kernel(const float* __restrict__ src, int slda,
                              u16* __restrict__ dst, int dld, int cols) {
  const int r = blockIdx.x;
  for (int c = threadIdx.x; c < cols; c += blockDim.x)
    dst[(size_t)r * dld + c] = f2bf(src[(size_t)r * slda + c]);
}

// ---------- fused box geometry + pos MLP + emb1 gather ----------
__global__ __launch_bounds__(256) void prep_obj(
    const float* __restrict__ boxes,
    const float* __restrict__ bb1w, const float* __restrict__ bb1b,
    const float* __restrict__ bb2w, const float* __restrict__ bb2b,
    const float* __restrict__ emb1, const int* __restrict__ labels,
    u16* __restrict__ obj_in) {
  __shared__ float W1[288];
  __shared__ float W2[4096];
  __shared__ float P1[8][33];
  const int tid = threadIdx.x;
  for (int i = tid; i < 288; i += 256) W1[i] = bb1w[i];
  for (int i = tid; i < 4096; i += 256) W2[i] = bb2w[i];
  __syncthreads();
  const int r8 = tid >> 5, sub = tid & 31;
  const int row = blockIdx.x * 8 + r8;
  const float x1 = boxes[row * 4], y1 = boxes[row * 4 + 1];
  const float x2 = boxes[row * 4 + 2], y2 = boxes[row * 4 + 3];
  const float w = x2 - x1 + 1.f, h = y2 - y1 + 1.f;
  const float bi[9] = {w / 800.f, h / 600.f, (x1 + 0.5f * w) / 800.f, (y1 + 0.5f * h) / 600.f,
                       x1 / 800.f, y1 / 600.f, x2 / 800.f, y2 / 600.f, w * h / 480000.f};
  float p = bb1b[sub];
#pragma unroll
  for (int j = 0; j < 9; ++j) p += bi[j] * W1[sub * 9 + j];
  P1[r8][sub] = fmaxf(p, 0.f);
  __syncthreads();
#pragma unroll
  for (int jo = 0; jo < 4; ++jo) {
    const int o = sub + jo * 32;
    float a = bb2b[o];
#pragma unroll
    for (int j2 = 0; j2 < 32; ++j2) a += P1[r8][j2] * W2[o * 32 + j2];
    obj_in[(size_t)row * 1408 + 1280 + o] = f2bf(fmaxf(a, 0.f));
  }
  const int l = labels[row];
#pragma unroll
  for (int k = 0; k < 8; ++k)
    obj_in[(size_t)row * 1408 + 1024 + sub + k * 32] = f2bf(emb1[(size_t)l * 256 + sub + k * 32]);
}

// ---------- merged emb2 gather + pair gather ----------
__global__ void gather_pair(const float* __restrict__ emb2, const int* __restrict__ labels,
                            u16* __restrict__ edge_in,               // [1280][768]
                            const int* __restrict__ idx, u16* __restrict__ pair) {
  const int r = blockIdx.x;
  const int tid = threadIdx.x;
  if (r < cN) {
    const int l = labels[r];
    edge_in[(size_t)r * 768 + 512 + tid] = f2bf(emb2[(size_t)l * cEMB + tid]);
  }
  const int b = r >> 8, rr = r & 255;
  const int i0 = idx[(size_t)(b * cRPI + rr) * 2 + 0];
  const int i1 = idx[(size_t)(b * cRPI + rr) * 2 + 1];
  const u16* hsrc = edge_in + (size_t)(b * cM + i0) * 768;
  const u16* tsrc = edge_in + (size_t)(b * cM + i1) * 768;
  u16* p = pair + (size_t)r * 1024;
  for (int c = tid; c < cHID; c += blockDim.x) {
    p[c] = hsrc[c];
    p[cHID + c] = tsrc[c];
  }
}

// fused attention per (b,h): qkv bf16 in, bf16 out (vectorized K/V fill)
__global__ __launch_bounds__(256) void attn_kernel(const u16* __restrict__ qkv,
                                                   u16* __restrict__ o) {
  __shared__ float Ks[80][65];
  __shared__ float Vs[80][65];
  const int bh = blockIdx.x;
  const int b = bh >> 3, h = bh & 7;
  const int tid = threadIdx.x;
  const u16* base = qkv + (size_t)(b * cM) * 1536 + h * 64;

  for (int e = tid; e < 640; e += 256) {
    const int r = e >> 3, d0 = (e & 7) * 8;
    const bf8_t kv = *(const bf8_t*)&base[(size_t)r * 1536 + 512 + d0];
    const bf8_t vv = *(const bf8_t*)&base[(size_t)r * 1536 + 1024 + d0];
#pragma unroll
    for (int j = 0; j < 8; ++j) {
      Ks[r][d0 + j] = bf2f((u16)kv[j]);
      Vs[r][d0 + j] = bf2f((u16)vv[j]);
    }
  }
  __syncthreads();

  const int wave = tid >> 6, lane = tid & 63;
  const int r0 = blockIdx.y * 16;
  for (int r = r0 + wave; r < r0 + 16; r += 4) {
    const float qd = bf2f(base[(size_t)r * 1536 + lane]);
    const int c2 = 64 + lane;
    const int c2c = (c2 < 80) ? c2 : 0;
    float s0 = 0.f, s1 = 0.f;
#pragma unroll 8
    for (int d = 0; d < 64; ++d) {
      const float qv = __shfl(qd, d);
      s0 += qv * Ks[lane][d];
      s1 += qv * Ks[c2c][d];
    }
    s0 *= 0.125f;
    s1 = (c2 < 80) ? s1 * 0.125f : -1e30f;
    const float mx = wave_max(fmaxf(s0, s1));
    const float p0 = __expf(s0 - mx);
    const float p1 = (c2 < 80) ? __expf(s1 - mx) : 0.f;
    const float ssum = wave_sum(p0 + p1);

    float od = 0.f;
#pragma unroll 8
    for (int c = 0; c < 64; ++c) od += __shfl(p0, c) * Vs[c][lane];
#pragma unroll
    for (int c = 0; c < 16; ++c) od += __shfl(p1, c) * Vs[64 + c][lane];
    od /= ssum;
    o[(size_t)(b * cM + r) * cHID + h * 64 + lane] = f2bf(od);
  }
}

// LayerNorm: 4 rows/block, 1 wave/row, fp32 out + bf16 mirror
__global__ __launch_bounds__(256) void ln_kernel(
    const float* __restrict__ in, float* __restrict__ outF,
    u16* __restrict__ outH, int ldh,
    const float* __restrict__ g, const float* __restrict__ bta) {
  const int row = blockIdx.x * 4 + (threadIdx.x >> 6);
  const int lane = threadIdx.x & 63;
  const float* x = in + (size_t)row * cHID;
  float v[8];
  float s = 0.f;
#pragma unroll
  for (int i = 0; i < 8; ++i) { v[i] = x[lane + i * 64]; s += v[i]; }
  s = wave_sum(s);
  const float mean = s * (1.f / 512.f);
  float vs = 0.f;
#pragma unroll
  for (int i = 0; i < 8; ++i) { const float d = v[i] - mean; vs += d * d; }
  vs = wave_sum(vs);
  const float inv = rsqrtf(vs * (1.f / 512.f) + 1e-5f);
#pragma unroll
  for (int i = 0; i < 8; ++i) {
    const int c = lane + i * 64;
    const float y = (v[i] - mean) * inv * g[c] + bta[c];
    outF[(size_t)row * cHID + c] = y;
    outH[(size_t)row * ldh + c] = f2bf(y);
  }
}

__global__ void mean_kernel(const float* __restrict__ x, u16* __restrict__ gctx_h) {
  const int b = blockIdx.x;
  const int c = threadIdx.x;  // 512
  float s = 0.f;
  for (int m = 0; m < cM; ++m) s += x[(size_t)(b * cM + m) * cHID + c];
  gctx_h[(size_t)b * cHID + c] = f2bf(s * (1.f / 80.f));
}

__global__ void reduce8_kernel(const float* __restrict__ p, const float* __restrict__ bias,
                               u16* __restrict__ outH) {
  const int idx = blockIdx.x * 256 + threadIdx.x;
  constexpr int total = cN * cREP;
  if (idx >= total) return;
  float v = bias[idx & 1023];
#pragma unroll
  for (int z = 0; z < 8; ++z) v += p[(size_t)z * total + idx];
  outH[idx] = f2bf(fmaxf(v, 0.f));
}

__global__ void freduce_kernel(const float* __restrict__ p, const float* __restrict__ biasc,
                               float* __restrict__ out) {
  const int idx = blockIdx.x * 256 + threadIdx.x;
  if (idx >= cR * cRELC) return;
  const int r = idx / cRELC, c = idx - r * cRELC;
  float v = biasc[c];
#pragma unroll
  for (int z = 0; z < 4; ++z) v += p[(size_t)z * cR * 64 + (size_t)r * 64 + c];
  out[idx] = v;
}

// ---------- encoder: 7 dispatches per layer, 32x32 GEMM tiles (R6 proven) ----------
static void run_encoder(hipStream_t s, float* x, u16* xh, u16* qkvh, u16* attn_h,
                        float* res1, u16* f_h,
                        const u16* qkvw, const float* qkvb,
                        const u16* outw, const float* outb,
                        const u16* f1w, const float* f1b,
                        const u16* f2w, const float* f2b,
                        const float* ln1s, const float* ln1b,
                        const float* ln2s, const float* ln2b,
                        u16* last_bf, int last_ld) {
  for (int l = 0; l < cL; ++l) {
    g16<32, 32>(s, xh, 512, qkvw + (size_t)l * 1536 * 512, 512, cN, 1536, 512,
                nullptr, 0, qkvh, 1536, qkvb + l * 1536, nullptr, 0, 0, 0);
    attn_kernel<<<dim3(cB * cNH, 5), 256, 0, s>>>(qkvh, attn_h);
    g16<32, 32>(s, attn_h, 512, outw + (size_t)l * 512 * 512, 512, cN, 512, 512,
                res1, 512, nullptr, 0, outb + l * 512, x, 512, 1, 0);
    ln_kernel<<<cN / 4, 256, 0, s>>>(res1, x, xh, 512, ln1s + l * 512, ln1b + l * 512);
    g16<32, 32>(s, xh, 512, f1w + (size_t)l * 512 * 512, 512, cN, 512, 512,
                nullptr, 0, f_h, 512, f1b + l * 512, nullptr, 0, 0, 1);
    g16<32, 32>(s, f_h, 512, f2w + (size_t)l * 512 * 512, 512, cN, 512, 512,
                res1, 512, nullptr, 0, f2b + l * 512, x, 512, 1, 0);
    const bool last = (l == cL - 1);
    ln_kernel<<<cN / 4, 256, 0, s>>>(res1, x, last ? last_bf : xh, last ? last_ld : 512,
                                     ln2s + l * 512, ln2b + l * 512);
  }
}

// ===== workspace layout (bytes) =====
constexpr size_t OFF_FEAT  = 0;
constexpr size_t OFF_FE1W  = 32112640;
constexpr size_t OFF_PART  = 57802752;   // 8*1280*1024*4
constexpr size_t P_END     = 99745792;
constexpr size_t OFF_PAIR  = 0;
constexpr size_t OFF_FINAL = 8388608;
constexpr size_t OFF_OBJIN = 33554432;
constexpr size_t OFF_QKVH  = 37158912;
constexpr size_t OFF_X     = 41091072;
constexpr size_t OFF_XH    = 43712512;
constexpr size_t OFF_ATTN  = 45023232;
constexpr size_t OFF_RES   = 46333952;
constexpr size_t OFF_FH    = 48955392;
constexpr size_t OFF_EDGE  = 50266112;   // ends 52,232,192

extern "C" void kernel_launch(void* const* d_in, const int* in_sizes, int n_in,
                              void* d_out, int out_size, void* d_ws, size_t ws_size,
                              hipStream_t stream) {
  (void)in_sizes; (void)n_in; (void)out_size; (void)ws_size;

  const float* features = (const float*)d_in[0];
  const float* unionf   = (const float*)d_in[1];
  const float* boxes    = (const float*)d_in[2];
  const int*   labels   = (const int*)d_in[4];
  const int*   relidx   = (const int*)d_in[5];
  const float* fe1_w = (const float*)d_in[6];
  const float* fe1_b = (const float*)d_in[7];
  const float* fe2_w = (const float*)d_in[8];
  const float* fe2_b = (const float*)d_in[9];
  const float* emb1  = (const float*)d_in[10];
  const float* emb2  = (const float*)d_in[11];
  const float* bb1_w = (const float*)d_in[12];
  const float* bb1_b = (const float*)d_in[13];
  const float* bb2_w = (const float*)d_in[14];
  const float* bb2_b = (const float*)d_in[15];
  const float* lobj_w = (const float*)d_in[16];
  const float* lobj_b = (const float*)d_in[17];
  const float* ledge_w = (const float*)d_in[18];
  const float* ledge_b = (const float*)d_in[19];
  const float* oqkv_w = (const float*)d_in[20];
  const float* oqkv_b = (const float*)d_in[21];
  const float* oout_w = (const float*)d_in[22];
  const float* oout_b = (const float*)d_in[23];
  const float* of1_w = (const float*)d_in[24];
  const float* of1_b = (const float*)d_in[25];
  const float* of2_w = (const float*)d_in[26];
  const float* of2_b = (const float*)d_in[27];
  const float* oln1_s = (const float*)d_in[28];
  const float* oln1_b = (const float*)d_in[29];
  const float* oln2_s = (const float*)d_in[30];
  const float* oln2_b = (const float*)d_in[31];
  const float* eqkv_w = (const float*)d_in[32];
  const float* eqkv_b = (const float*)d_in[33];
  const float* eout_w = (const float*)d_in[34];
  const float* eout_b = (const float*)d_in[35];
  const float* ef1_w = (const float*)d_in[36];
  const float* ef1_b = (const float*)d_in[37];
  const float* ef2_w = (const float*)d_in[38];
  const float* ef2_b = (const float*)d_in[39];
  const float* eln1_s = (const float*)d_in[40];
  const float* eln1_b = (const float*)d_in[41];
  const float* eln2_s = (const float*)d_in[42];
  const float* eln2_b = (const float*)d_in[43];
  const float* pcat_w = (const float*)d_in[44];
  const float* pcat_b = (const float*)d_in[45];
  const float* fuse_w = (const float*)d_in[46];
  const float* fuse_b = (const float*)d_in[47];
  const float* cpx_w  = (const float*)d_in[48];
  const float* cpx_b  = (const float*)d_in[49];
  const float* dpath_w = (const float*)d_in[50];
  const float* dpath_b = (const float*)d_in[51];

  char* wsb = (char*)d_ws;
  u16* feat_h  = (u16*)(wsb + OFF_FEAT);
  u16* fe1w_h  = (u16*)(wsb + OFF_FE1W);
  float* part  = (float*)(wsb + OFF_PART);
  u16* pair    = (u16*)(wsb + OFF_PAIR);
  u16* finalb  = (u16*)(wsb + OFF_FINAL);
  u16* obj_in  = (u16*)(wsb + OFF_OBJIN);
  u16* qkvh    = (u16*)(wsb + OFF_QKVH);
  float* x     = (float*)(wsb + OFF_X);
  u16* xh      = (u16*)(wsb + OFF_XH);
  u16* attn_h  = (u16*)(wsb + OFF_ATTN);
  float* res1  = (float*)(wsb + OFF_RES);
  u16* f_h     = (u16*)(wsb + OFF_FH);
  u16* edge_in = (u16*)(wsb + OFF_EDGE);

  size_t off = P_END;
  auto alloc = [&](size_t bytes) { char* p = wsb + off; off = (off + bytes + 255) & ~(size_t)255; return p; };
  u16* wblock   = (u16*)alloc(W_WEND * 2);
  u16* catw     = (u16*)alloc(313344);
  float* biasc  = (float*)alloc(256);
  u16* bf0h     = (u16*)alloc(2621440);
  u16* gctx_h   = (u16*)alloc(65536);
  float* gcproj = (float*)alloc(262144);
  float* fpart  = (float*)alloc(4194304);

  const u16* fe2w_h   = wblock + W_FE2;
  const u16* lobjw_h  = wblock + W_LOBJ;
  const u16* ledgew_h = wblock + W_LEDGE;
  const u16* pcatw_h  = wblock + W_PCAT;
  const u16* fusew_h  = wblock + W_FUSE;

  // --- 1) converts (3 dispatches) ---
  conv_big2<<<2048, 256, 0, stream>>>(features, fe1_w, feat_h, fe1w_h);
  EncSrcs es = {fe2_w, lobj_w, ledge_w, oqkv_w, oout_w, of1_w, of2_w,
                eqkv_w, eout_w, ef1_w, ef2_w, pcat_w, fuse_w};
  conv_enc<<<2048, 256, 0, stream>>>(es, wblock);
  conv_cat<<<160, 256, 0, stream>>>(cpx_w, dpath_w, cpx_b, dpath_b, catw, biasc);

  // --- 2) fe1 split-K=8 (K-chunk == XCD, 64x128 tiles) + reduce ---
  gemm_fe1<<<dim3(8, 160), 256, 0, stream>>>(feat_h, fe1w_h, part);
  reduce8_kernel<<<(cN * cREP + 255) / 256, 256, 0, stream>>>(part, fe1_b, bf0h);

  // --- 3) box path + emb1 gather ---
  prep_obj<<<cN / 8, 256, 0, stream>>>(boxes, bb1_w, bb1_b, bb2_w, bb2_b, emb1, labels, obj_in);

  // --- 4) fe2 -> obj_in[:, :1024] ---
  g16<32, 32>(stream, bf0h, 1024, fe2w_h, 1024, cN, cREP, cREP,
              nullptr, 0, obj_in, 1408, fe2_b, nullptr, 0, 0, 1);

  // --- 5) obj_rep -> x, xh ---
  g16<32, 32>(stream, obj_in, 1408, lobjw_h, 1408, cN, cHID, 1408,
              x, 512, xh, 512, lobj_b, nullptr, 0, 0, 0);

  // --- 6) object encoder ---
  run_encoder(stream, x, xh, qkvh, attn_h, res1, f_h,
              wblock + W_OQKV, oqkv_b, wblock + W_OOUT, oout_b,
              wblock + W_OF1, of1_b, wblock + W_OF2, of2_b,
              oln1_s, oln1_b, oln2_s, oln2_b, edge_in, 768);

  // --- 7) emb2 gather + pair gather (merged) ---
  gather_pair<<<cR, 256, 0, stream>>>(emb2, labels, edge_in, relidx, pair);

  // --- 8) edge encoder ---
  g16<32, 32>(stream, edge_in, 768, ledgew_h, 768, cN, cHID, 768,
              x, 512, xh, 512, ledge_b, nullptr, 0, 0, 0);
  run_encoder(stream, x, xh, qkvh, attn_h, res1, f_h,
              wblock + W_EQKV, eqkv_b, wblock + W_EOUT, eout_b,
              wblock + W_EF1, ef1_b, wblock + W_EF2, ef2_b,
              eln1_s, eln1_b, eln2_s, eln2_b, xh, 512);
  mean_kernel<<<cB, cHID, 0, stream>>>(x, gctx_h);

  // --- 9) gcproj = gctx @ fuse_w[:,1024:]^T + fuse_b ---
  g16<32, 64>(stream, gctx_h, 512, fusew_h + 1024, 1536, 64, cREP, 512,
              gcproj, 1024, nullptr, 0, fuse_b, nullptr, 0, 0, 0);

  // --- 10) final feature block ---
  conv2d_kernel<<<cR, 256, 0, stream>>>(unionf, 1024, finalb + 1024, 3072, 1024);
  g16<128, 64>(stream, pair, 1024, pcatw_h, 1024, cR, cREP, 1024,
               nullptr, 0, finalb + 2048, 3072, pcat_b, nullptr, 0, 0, 0);
  g16<128, 64>(stream, finalb + 2048, 3072, fusew_h, 1536, cR, cREP, 1024,
               nullptr, 0, finalb, 3072, nullptr, gcproj, 1024, 2, 1);

  // --- 11) rel_logits ---
  gemm_h<64, 64, true><<<dim3(1, 64, 4), 256, 0, stream>>>(
      finalb, 3072, catw, 3072, cR, cRELC, 3072 / 4, fpart, 64,
      nullptr, 0, nullptr, nullptr, 0, 0, 0);
  freduce_kernel<<<(cR * cRELC + 255) / 256, 256, 0, stream>>>(fpart, biasc, (float*)d_out);
}

// Round 16
// 870.101 us; speedup vs baseline: 1.0182x; 1.0125x over previous
//
#include <hip/hip_runtime.h>
#include <hip/hip_bf16.h>
#include <cstdint>

#define DEV_INLINE __device__ __forceinline__

using u16 = unsigned short;
typedef __attribute__((ext_vector_type(8))) short bf8_t;   // 8 x bf16 (4 VGPR)
typedef __attribute__((ext_vector_type(4))) float f32x4;

constexpr int cB = 16, cM = 80, cRPI = 256;
constexpr int cN = cB * cM;        // 1280
constexpr int cR = cB * cRPI;      // 4096
constexpr int cDF = 12544, cREP = 1024, cEMB = 256, cHID = 512, cNH = 8, cL = 4;
constexpr int cRELC = 51;

DEV_INLINE u16 f2bf(float x) { return __builtin_bit_cast(u16, __float2bfloat16(x)); }
DEV_INLINE float bf2f(u16 u) { return __bfloat162float(__builtin_bit_cast(__hip_bfloat16, u)); }

DEV_INLINE float wave_max(float v) {
#pragma unroll
  for (int o = 32; o; o >>= 1) v = fmaxf(v, __shfl_xor(v, o));
  return v;
}
DEV_INLINE float wave_sum(float v) {
#pragma unroll
  for (int o = 32; o; o >>= 1) v += __shfl_xor(v, o);
  return v;
}

DEV_INLINE void gl_lds16(const u16* gp, char* lp) {
  __builtin_amdgcn_global_load_lds(
      (const __attribute__((address_space(1))) void*)gp,
      (__attribute__((address_space(3))) void*)lp, 16, 0, 0);
}

// XCD-bijective remap (m204)
DEV_INLINE void xcd_remap(int& bx, int& by) {
  const int gx = gridDim.x;
  const int nwg = gx * gridDim.y;
  const int id = blockIdx.x + gx * blockIdx.y;
  const int q = nwg >> 3, r = nwg & 7;
  const int x = id & 7, k = id >> 3;
  const int idp = (x < r) ? x * (q + 1) + k : r * (q + 1) + (x - r) * q + k;
  bx = idp % gx;
  by = idp / gx;
}

// =====================================================================
// fe1 GEMM (R13-proven best): bf16, split-K=8, 128x128 tiles, grid (8,80).
// blockIdx.x = K-chunk -> physical XCD == K-chunk: each XCD streams only
// its 7.2MB K-slice (FETCH 131->29MB measured). bn-fast tile order keeps
// the B K-slice L2-resident.
// =====================================================================
__global__ __launch_bounds__(256) void gemm_fe1(
    const u16* __restrict__ A, const u16* __restrict__ Bw,
    float* __restrict__ outF)
{
  constexpr int lda = cDF, ldb = cDF, ldc = cREP;
  constexpr int Klen = cDF / 8;    // 1568
  __shared__ u16 As[2][128 * 32];
  __shared__ u16 Bs[2][128 * 32];
  const int tid = threadIdx.x;
  const int wid = tid >> 6, lane = tid & 63;
  const int l15 = lane & 15, l4 = lane >> 4;
  const int z = blockIdx.x;                 // K-chunk == XCD
  const int tile = blockIdx.y;              // 0..79
  const int bm = (tile >> 3) * 128;         // 10 row panels (slow)
  const int bn = (tile & 7) * 128;          // 8 col panels (fast)
  const int wr = wid >> 1, wc = wid & 1;
  const int kbase = z * Klen;

  f32x4 acc[4][4] = {};

  auto stage = [&](int buf, int ks) {
    const int k0 = kbase + (ks << 5);
#pragma unroll
    for (int i = 0; i < 2; ++i) {
      const int cA = i * 256 + tid;
      const int row = cA >> 2, seg = cA & 3;
      const int sseg = seg ^ (row & 3);
      gl_lds16(A + (size_t)(bm + row) * lda + k0 + sseg * 8,
               (char*)As[buf] + (size_t)(cA - lane) * 16);
    }
#pragma unroll
    for (int i = 0; i < 2; ++i) {
      const int cB2 = i * 256 + tid;
      const int row = cB2 >> 2, seg = cB2 & 3;
      const int sseg = seg ^ (row & 3);
      gl_lds16(Bw + (size_t)(bn + row) * ldb + k0 + sseg * 8,
               (char*)Bs[buf] + (size_t)(cB2 - lane) * 16);
    }
  };

  const int nk = Klen >> 5;   // 49
  stage(0, 0);
  __syncthreads();

  for (int ks = 0; ks < nk; ++ks) {
    const int cur = ks & 1;
    if (ks + 1 < nk) stage(cur ^ 1, ks + 1);

    bf8_t af[4], bfr[4];
#pragma unroll
    for (int m = 0; m < 4; ++m) {
      const int r = wr * 64 + m * 16 + l15;
      const int g = l4 ^ (r & 3);
      af[m] = *(const bf8_t*)&As[cur][r * 32 + g * 8];
    }
#pragma unroll
    for (int n = 0; n < 4; ++n) {
      const int r = wc * 64 + n * 16 + l15;
      const int g = l4 ^ (r & 3);
      bfr[n] = *(const bf8_t*)&Bs[cur][r * 32 + g * 8];
    }
#pragma unroll
    for (int m = 0; m < 4; ++m)
#pragma unroll
      for (int n = 0; n < 4; ++n)
        acc[m][n] = __builtin_amdgcn_mfma_f32_16x16x32_bf16(af[m], bfr[n], acc[m][n], 0, 0, 0);
    __syncthreads();
  }

  float* po = outF + (size_t)z * cN * ldc;
#pragma unroll
  for (int m = 0; m < 4; ++m)
#pragma unroll
    for (int n = 0; n < 4; ++n) {
      const int ccol = bn + wc * 64 + n * 16 + l15;
#pragma unroll
      for (int g = 0; g < 4; ++g) {
        const int r = bm + wr * 64 + m * 16 + l4 * 4 + g;
        po[(size_t)r * ldc + ccol] = acc[m][n][g];
      }
    }
}

// =====================================================================
// bf16 MFMA GEMM (general K): dbuf BK=32 (R6 proven)
// =====================================================================
template <int BM, int BN, bool SPLIT>
__global__ __launch_bounds__(256) void gemm_h(
    const u16* __restrict__ A, int lda,
    const u16* __restrict__ Bw, int ldb,
    int Mr, int Nr, int Klen,
    float* __restrict__ outF, int ldc,
    u16* __restrict__ outH, int ldh,
    const float* __restrict__ bias,
    const float* __restrict__ res, int resld, int resmode,
    int relu)
{
  constexpr int MF = BM > 32 ? BM / 32 : 1, NF = BN > 32 ? BN / 32 : 1;
  constexpr int ACH = BM * 4, BCH = BN * 4;
  __shared__ u16 As[2][BM * 32];
  __shared__ u16 Bs[2][BN * 32];
  const int tid = threadIdx.x;
  const int wid = tid >> 6, lane = tid & 63;
  const int l15 = lane & 15, l4 = lane >> 4;
  int bx, by;
  xcd_remap(bx, by);
  const int bm = by * BM, bn = bx * BN;
  const int wr = wid >> 1, wc = wid & 1;
  const int kbase = SPLIT ? blockIdx.z * Klen : 0;

  f32x4 acc[MF][NF] = {};

  auto stage = [&](int buf, int ks) {
    const int k0 = kbase + (ks << 5);
#pragma unroll
    for (int i = 0; i < (ACH + 255) / 256; ++i) {
      const int cA = i * 256 + tid;
      if (ACH % 256 == 0 || cA < ACH) {
        const int row = cA >> 2, seg = cA & 3;
        const int sseg = seg ^ (row & 3);
        gl_lds16(A + (size_t)(bm + row) * lda + k0 + sseg * 8,
                 (char*)As[buf] + (size_t)(cA - lane) * 16);
      }
    }
#pragma unroll
    for (int i = 0; i < (BCH + 255) / 256; ++i) {
      const int cBp = i * 256 + ((tid + 128) & 255);
      if (BCH % 256 == 0 || cBp < BCH) {
        const int row = cBp >> 2, seg = cBp & 3;
        const int sseg = seg ^ (row & 3);
        int brow = bn + row; if (brow > Nr - 1) brow = Nr - 1;
        gl_lds16(Bw + (size_t)brow * ldb + k0 + sseg * 8,
                 (char*)Bs[buf] + (size_t)(cBp - lane) * 16);
      }
    }
  };

  const int nk = Klen >> 5;
  stage(0, 0);
  __syncthreads();

  for (int ks = 0; ks < nk; ++ks) {
    const int cur = ks & 1;
    if (ks + 1 < nk) stage(cur ^ 1, ks + 1);

    bf8_t af[MF], bfr[NF];
#pragma unroll
    for (int m = 0; m < MF; ++m) {
      const int r = wr * (BM / 2) + m * 16 + l15;
      const int g = l4 ^ (r & 3);
      af[m] = *(const bf8_t*)&As[cur][r * 32 + g * 8];
    }
#pragma unroll
    for (int n = 0; n < NF; ++n) {
      const int r = wc * (BN / 2) + n * 16 + l15;
      const int g = l4 ^ (r & 3);
      bfr[n] = *(const bf8_t*)&Bs[cur][r * 32 + g * 8];
    }
#pragma unroll
    for (int m = 0; m < MF; ++m)
#pragma unroll
      for (int n = 0; n < NF; ++n)
        acc[m][n] = __builtin_amdgcn_mfma_f32_16x16x32_bf16(af[m], bfr[n], acc[m][n], 0, 0, 0);
    __syncthreads();
  }

  if (SPLIT) {
    float* po = outF + (size_t)blockIdx.z * Mr * ldc;
#pragma unroll
    for (int m = 0; m < MF; ++m)
#pragma unroll
      for (int n = 0; n < NF; ++n) {
        const int ccol = bn + wc * (BN / 2) + n * 16 + l15;
        if (ccol >= Nr) continue;
#pragma unroll
        for (int g = 0; g < 4; ++g) {
          const int r = bm + wr * (BM / 2) + m * 16 + l4 * 4 + g;
          po[(size_t)r * ldc + ccol] = acc[m][n][g];
        }
      }
  } else {
#pragma unroll
    for (int m = 0; m < MF; ++m)
#pragma unroll
      for (int n = 0; n < NF; ++n) {
        const int ccol = bn + wc * (BN / 2) + n * 16 + l15;
        if (ccol >= Nr) continue;
        const float bv = bias ? bias[ccol] : 0.f;
#pragma unroll
        for (int g = 0; g < 4; ++g) {
          const int r = bm + wr * (BM / 2) + m * 16 + l4 * 4 + g;
          float v = acc[m][n][g] + bv;
          if (resmode == 1) v += res[(size_t)r * resld + ccol];
          else if (resmode == 2) v += res[(size_t)(r >> 8) * resld + ccol];
          if (relu) v = fmaxf(v, 0.f);
          if (outF) outF[(size_t)r * ldc + ccol] = v;
          if (outH) outH[(size_t)r * ldh + ccol] = f2bf(v);
        }
      }
  }
}

template <int BM, int BN>
static void g16(hipStream_t s, const u16* A, int lda, const u16* W, int ldb,
                int M, int N, int K, float* outF, int ldc, u16* outH, int ldh,
                const float* bias, const float* res, int resld, int resmode, int relu) {
  dim3 g((N + BN - 1) / BN, M / BM);
  gemm_h<BM, BN, false><<<g, 256, 0, s>>>(A, lda, W, ldb, M, N, K, outF, ldc, outH, ldh,
                                          bias, res, resld, resmode, relu);
}

// ---------- converts: 3 kernels (R6/R13 proven) ----------
__global__ void conv_big2(const float* __restrict__ f, const float* __restrict__ w,
                          u16* __restrict__ fh, u16* __restrict__ wh) {
  constexpr int N1 = cN * cDF / 4;
  constexpr int N2 = cREP * cDF / 4;
  for (int i = blockIdx.x * 256 + threadIdx.x; i < N1 + N2; i += gridDim.x * 256) {
    const float4 v = (i < N1) ? ((const float4*)f)[i] : ((const float4*)w)[i - N1];
    ushort4 o = {f2bf(v.x), f2bf(v.y), f2bf(v.z), f2bf(v.w)};
    if (i < N1) ((ushort4*)fh)[i] = o; else ((ushort4*)wh)[i - N1] = o;
  }
}

constexpr size_t W_FE2 = 0, W_LOBJ = W_FE2 + 1048576, W_LEDGE = W_LOBJ + 720896,
  W_OQKV = W_LEDGE + 393216, W_OOUT = W_OQKV + 3145728, W_OF1 = W_OOUT + 1048576,
  W_OF2 = W_OF1 + 1048576, W_EQKV = W_OF2 + 1048576, W_EOUT = W_EQKV + 3145728,
  W_EF1 = W_EOUT + 1048576, W_EF2 = W_EF1 + 1048576, W_PCAT = W_EF2 + 1048576,
  W_FUSE = W_PCAT + 1048576, W_WEND = W_FUSE + 1572864;   // 16,580,608 u16

struct EncSrcs {
  const float *fe2, *lobj, *ledge, *oqkv, *oout, *of1, *of2,
              *eqkv, *eout, *ef1, *ef2, *pcat, *fuse;
};

__global__ void conv_enc(EncSrcs S, u16* __restrict__ wb) {
#define SEG(nm, OFF, PRE, LEN) \
  if (i < (PRE) + (LEN)) { \
    const float4 v = ((const float4*)S.nm)[i - (PRE)]; \
    ushort4 o = {f2bf(v.x), f2bf(v.y), f2bf(v.z), f2bf(v.w)}; \
    ((ushort4*)(wb + (OFF)))[i - (PRE)] = o; \
  } else
  for (int i = blockIdx.x * 256 + threadIdx.x; i < (int)(W_WEND / 4); i += gridDim.x * 256) {
    SEG(fe2,  W_FE2,   0,       262144)
    SEG(lobj, W_LOBJ,  262144,  180224)
    SEG(ledge,W_LEDGE, 442368,  98304)
    SEG(oqkv, W_OQKV,  540672,  786432)
    SEG(oout, W_OOUT,  1327104, 262144)
    SEG(of1,  W_OF1,   1589248, 262144)
    SEG(of2,  W_OF2,   1851392, 262144)
    SEG(eqkv, W_EQKV,  2113536, 786432)
    SEG(eout, W_EOUT,  2899968, 262144)
    SEG(ef1,  W_EF1,   3162112, 262144)
    SEG(ef2,  W_EF2,   3424256, 262144)
    SEG(pcat, W_PCAT,  3686400, 262144)
    SEG(fuse, W_FUSE,  3948544, 393216)
    { }
  }
#undef SEG
}

__global__ void conv_cat(const float* __restrict__ cpx, const float* __restrict__ dpath,
                         const float* __restrict__ cb, const float* __restrict__ db,
                         u16* __restrict__ catw, float* __restrict__ biasc) {
  constexpr int N1 = cRELC * 512;
  constexpr int N2 = cRELC * 256;
  const int i0 = blockIdx.x * 256 + threadIdx.x;
  if (blockIdx.x == 0 && threadIdx.x < cRELC) biasc[threadIdx.x] = cb[threadIdx.x] + db[threadIdx.x];
  for (int i = i0; i < N1 + N2; i += gridDim.x * 256) {
    if (i < N1) {
      const int r = i >> 9, c = i & 511;
      const float4 v = ((const float4*)cpx)[i];
      ushort4 o = {f2bf(v.x), f2bf(v.y), f2bf(v.z), f2bf(v.w)};
      ((ushort4*)catw)[r * 768 + c] = o;
    } else {
      const int j = i - N1, r = j >> 8, c = j & 255;
      const float4 v = ((const float4*)dpath)[j];
      ushort4 o = {f2bf(v.x), f2bf(v.y), f2bf(v.z), f2bf(v.w)};
      ((ushort4*)catw)[r * 768 + 512 + c] = o;
    }
  }
}

__global__ void conv2d_kernel(const float* __restrict__ src, int slda,
                              u16* __restrict__ dst, int dld, int cols) {
  const int r = blockIdx.x;
  for (int c = threadIdx.x; c < cols; c += blockDim.x)
    dst[(size_t)r * dld + c] = f2bf(src[(size_t)r * slda + c]);
}

// ---------- fused box geometry + pos MLP + emb1 gather ----------
__global__ __launch_bounds__(256) void prep_obj(
    const float* __restrict__ boxes,
    const float* __restrict__ bb1w, const float* __restrict__ bb1b,
    const float* __restrict__ bb2w, const float* __restrict__ bb2b,
    const float* __restrict__ emb1, const int* __restrict__ labels,
    u16* __restrict__ obj_in) {
  __shared__ float W1[288];
  __shared__ float W2[4096];
  __shared__ float P1[8][33];
  const int tid = threadIdx.x;
  for (int i = tid; i < 288; i += 256) W1[i] = bb1w[i];
  for (int i = tid; i < 4096; i += 256) W2[i] = bb2w[i];
  __syncthreads();
  const int r8 = tid >> 5, sub = tid & 31;
  const int row = blockIdx.x * 8 + r8;
  const float x1 = boxes[row * 4], y1 = boxes[row * 4 + 1];
  const float x2 = boxes[row * 4 + 2], y2 = boxes[row * 4 + 3];
  const float w = x2 - x1 + 1.f, h = y2 - y1 + 1.f;
  const float bi[9] = {w / 800.f, h / 600.f, (x1 + 0.5f * w) / 800.f, (y1 + 0.5f * h) / 600.f,
                       x1 / 800.f, y1 / 600.f, x2 / 800.f, y2 / 600.f, w * h / 480000.f};
  float p = bb1b[sub];
#pragma unroll
  for (int j = 0; j < 9; ++j) p += bi[j] * W1[sub * 9 + j];
  P1[r8][sub] = fmaxf(p, 0.f);
  __syncthreads();
#pragma unroll
  for (int jo = 0; jo < 4; ++jo) {
    const int o = sub + jo * 32;
    float a = bb2b[o];
#pragma unroll
    for (int j2 = 0; j2 < 32; ++j2) a += P1[r8][j2] * W2[o * 32 + j2];
    obj_in[(size_t)row * 1408 + 1280 + o] = f2bf(fmaxf(a, 0.f));
  }
  const int l = labels[row];
#pragma unroll
  for (int k = 0; k < 8; ++k)
    obj_in[(size_t)row * 1408 + 1024 + sub + k * 32] = f2bf(emb1[(size_t)l * 256 + sub + k * 32]);
}

// ---------- merged emb2 gather + pair gather ----------
__global__ void gather_pair(const float* __restrict__ emb2, const int* __restrict__ labels,
                            u16* __restrict__ edge_in,               // [1280][768]
                            const int* __restrict__ idx, u16* __restrict__ pair) {
  const int r = blockIdx.x;
  const int tid = threadIdx.x;
  if (r < cN) {
    const int l = labels[r];
    edge_in[(size_t)r * 768 + 512 + tid] = f2bf(emb2[(size_t)l * cEMB + tid]);
  }
  const int b = r >> 8, rr = r & 255;
  const int i0 = idx[(size_t)(b * cRPI + rr) * 2 + 0];
  const int i1 = idx[(size_t)(b * cRPI + rr) * 2 + 1];
  const u16* hsrc = edge_in + (size_t)(b * cM + i0) * 768;
  const u16* tsrc = edge_in + (size_t)(b * cM + i1) * 768;
  u16* p = pair + (size_t)r * 1024;
  for (int c = tid; c < cHID; c += blockDim.x) {
    p[c] = hsrc[c];
    p[cHID + c] = tsrc[c];
  }
}

// fused attention per (b,h): qkv bf16 in, bf16 out (vectorized K/V fill)
__global__ __launch_bounds__(256) void attn_kernel(const u16* __restrict__ qkv,
                                                   u16* __restrict__ o) {
  __shared__ float Ks[80][65];
  __shared__ float Vs[80][65];
  const int bh = blockIdx.x;
  const int b = bh >> 3, h = bh & 7;
  const int tid = threadIdx.x;
  const u16* base = qkv + (size_t)(b * cM) * 1536 + h * 64;

  for (int e = tid; e < 640; e += 256) {
    const int r = e >> 3, d0 = (e & 7) * 8;
    const bf8_t kv = *(const bf8_t*)&base[(size_t)r * 1536 + 512 + d0];
    const bf8_t vv = *(const bf8_t*)&base[(size_t)r * 1536 + 1024 + d0];
#pragma unroll
    for (int j = 0; j < 8; ++j) {
      Ks[r][d0 + j] = bf2f((u16)kv[j]);
      Vs[r][d0 + j] = bf2f((u16)vv[j]);
    }
  }
  __syncthreads();

  const int wave = tid >> 6, lane = tid & 63;
  const int r0 = blockIdx.y * 16;
  for (int r = r0 + wave; r < r0 + 16; r += 4) {
    const float qd = bf2f(base[(size_t)r * 1536 + lane]);
    const int c2 = 64 + lane;
    const int c2c = (c2 < 80) ? c2 : 0;
    float s0 = 0.f, s1 = 0.f;
#pragma unroll 8
    for (int d = 0; d < 64; ++d) {
      const float qv = __shfl(qd, d);
      s0 += qv * Ks[lane][d];
      s1 += qv * Ks[c2c][d];
    }
    s0 *= 0.125f;
    s1 = (c2 < 80) ? s1 * 0.125f : -1e30f;
    const float mx = wave_max(fmaxf(s0, s1));
    const float p0 = __expf(s0 - mx);
    const float p1 = (c2 < 80) ? __expf(s1 - mx) : 0.f;
    const float ssum = wave_sum(p0 + p1);

    float od = 0.f;
#pragma unroll 8
    for (int c = 0; c < 64; ++c) od += __shfl(p0, c) * Vs[c][lane];
#pragma unroll
    for (int c = 0; c < 16; ++c) od += __shfl(p1, c) * Vs[64 + c][lane];
    od /= ssum;
    o[(size_t)(b * cM + r) * cHID + h * 64 + lane] = f2bf(od);
  }
}

// LayerNorm: 4 rows/block, 1 wave/row, fp32 out + bf16 mirror
__global__ __launch_bounds__(256) void ln_kernel(
    const float* __restrict__ in, float* __restrict__ outF,
    u16* __restrict__ outH, int ldh,
    const float* __restrict__ g, const float* __restrict__ bta) {
  const int row = blockIdx.x * 4 + (threadIdx.x >> 6);
  const int lane = threadIdx.x & 63;
  const float* x = in + (size_t)row * cHID;
  float v[8];
  float s = 0.f;
#pragma unroll
  for (int i = 0; i < 8; ++i) { v[i] = x[lane + i * 64]; s += v[i]; }
  s = wave_sum(s);
  const float mean = s * (1.f / 512.f);
  float vs = 0.f;
#pragma unroll
  for (int i = 0; i < 8; ++i) { const float d = v[i] - mean; vs += d * d; }
  vs = wave_sum(vs);
  const float inv = rsqrtf(vs * (1.f / 512.f) + 1e-5f);
#pragma unroll
  for (int i = 0; i < 8; ++i) {
    const int c = lane + i * 64;
    const float y = (v[i] - mean) * inv * g[c] + bta[c];
    outF[(size_t)row * cHID + c] = y;
    outH[(size_t)row * ldh + c] = f2bf(y);
  }
}

__global__ void mean_kernel(const float* __restrict__ x, u16* __restrict__ gctx_h) {
  const int b = blockIdx.x;
  const int c = threadIdx.x;  // 512
  float s = 0.f;
  for (int m = 0; m < cM; ++m) s += x[(size_t)(b * cM + m) * cHID + c];
  gctx_h[(size_t)b * cHID + c] = f2bf(s * (1.f / 80.f));
}

__global__ void reduce8_kernel(const float* __restrict__ p, const float* __restrict__ bias,
                               u16* __restrict__ outH) {
  const int idx = blockIdx.x * 256 + threadIdx.x;
  constexpr int total = cN * cREP;
  if (idx >= total) return;
  float v = bias[idx & 1023];
#pragma unroll
  for (int z = 0; z < 8; ++z) v += p[(size_t)z * total + idx];
  outH[idx] = f2bf(fmaxf(v, 0.f));
}

__global__ void freduce_kernel(const float* __restrict__ p, const float* __restrict__ biasc,
                               float* __restrict__ out) {
  const int idx = blockIdx.x * 256 + threadIdx.x;
  if (idx >= cR * cRELC) return;
  const int r = idx / cRELC, c = idx - r * cRELC;
  float v = biasc[c];
#pragma unroll
  for (int z = 0; z < 4; ++z) v += p[(size_t)z * cR * 64 + (size_t)r * 64 + c];
  out[idx] = v;
}

// ---------- encoder: 7 dispatches per layer, 32x32 GEMM tiles (R6 proven) ----------
static void run_encoder(hipStream_t s, float* x, u16* xh, u16* qkvh, u16* attn_h,
                        float* res1, u16* f_h,
                        const u16* qkvw, const float* qkvb,
                        const u16* outw, const float* outb,
                        const u16* f1w, const float* f1b,
                        const u16* f2w, const float* f2b,
                        const float* ln1s, const float* ln1b,
                        const float* ln2s, const float* ln2b,
                        u16* last_bf, int last_ld) {
  for (int l = 0; l < cL; ++l) {
    g16<32, 32>(s, xh, 512, qkvw + (size_t)l * 1536 * 512, 512, cN, 1536, 512,
                nullptr, 0, qkvh, 1536, qkvb + l * 1536, nullptr, 0, 0, 0);
    attn_kernel<<<dim3(cB * cNH, 5), 256, 0, s>>>(qkvh, attn_h);
    g16<32, 32>(s, attn_h, 512, outw + (size_t)l * 512 * 512, 512, cN, 512, 512,
                res1, 512, nullptr, 0, outb + l * 512, x, 512, 1, 0);
    ln_kernel<<<cN / 4, 256, 0, s>>>(res1, x, xh, 512, ln1s + l * 512, ln1b + l * 512);
    g16<32, 32>(s, xh, 512, f1w + (size_t)l * 512 * 512, 512, cN, 512, 512,
                nullptr, 0, f_h, 512, f1b + l * 512, nullptr, 0, 0, 1);
    g16<32, 32>(s, f_h, 512, f2w + (size_t)l * 512 * 512, 512, cN, 512, 512,
                res1, 512, nullptr, 0, f2b + l * 512, x, 512, 1, 0);
    const bool last = (l == cL - 1);
    ln_kernel<<<cN / 4, 256, 0, s>>>(res1, x, last ? last_bf : xh, last ? last_ld : 512,
                                     ln2s + l * 512, ln2b + l * 512);
  }
}

// ===== workspace layout (bytes) =====
constexpr size_t OFF_FEAT  = 0;
constexpr size_t OFF_FE1W  = 32112640;
constexpr size_t OFF_PART  = 57802752;   // 8*1280*1024*4
constexpr size_t P_END     = 99745792;
constexpr size_t OFF_PAIR  = 0;
constexpr size_t OFF_FINAL = 8388608;
constexpr size_t OFF_OBJIN = 33554432;
constexpr size_t OFF_QKVH  = 37158912;
constexpr size_t OFF_X     = 41091072;
constexpr size_t OFF_XH    = 43712512;
constexpr size_t OFF_ATTN  = 45023232;
constexpr size_t OFF_RES   = 46333952;
constexpr size_t OFF_FH    = 48955392;
constexpr size_t OFF_EDGE  = 50266112;   // ends 52,232,192

extern "C" void kernel_launch(void* const* d_in, const int* in_sizes, int n_in,
                              void* d_out, int out_size, void* d_ws, size_t ws_size,
                              hipStream_t stream) {
  (void)in_sizes; (void)n_in; (void)out_size; (void)ws_size;

  const float* features = (const float*)d_in[0];
  const float* unionf   = (const float*)d_in[1];
  const float* boxes    = (const float*)d_in[2];
  const int*   labels   = (const int*)d_in[4];
  const int*   relidx   = (const int*)d_in[5];
  const float* fe1_w = (const float*)d_in[6];
  const float* fe1_b = (const float*)d_in[7];
  const float* fe2_w = (const float*)d_in[8];
  const float* fe2_b = (const float*)d_in[9];
  const float* emb1  = (const float*)d_in[10];
  const float* emb2  = (const float*)d_in[11];
  const float* bb1_w = (const float*)d_in[12];
  const float* bb1_b = (const float*)d_in[13];
  const float* bb2_w = (const float*)d_in[14];
  const float* bb2_b = (const float*)d_in[15];
  const float* lobj_w = (const float*)d_in[16];
  const float* lobj_b = (const float*)d_in[17];
  const float* ledge_w = (const float*)d_in[18];
  const float* ledge_b = (const float*)d_in[19];
  const float* oqkv_w = (const float*)d_in[20];
  const float* oqkv_b = (const float*)d_in[21];
  const float* oout_w = (const float*)d_in[22];
  const float* oout_b = (const float*)d_in[23];
  const float* of1_w = (const float*)d_in[24];
  const float* of1_b = (const float*)d_in[25];
  const float* of2_w = (const float*)d_in[26];
  const float* of2_b = (const float*)d_in[27];
  const float* oln1_s = (const float*)d_in[28];
  const float* oln1_b = (const float*)d_in[29];
  const float* oln2_s = (const float*)d_in[30];
  const float* oln2_b = (const float*)d_in[31];
  const float* eqkv_w = (const float*)d_in[32];
  const float* eqkv_b = (const float*)d_in[33];
  const float* eout_w = (const float*)d_in[34];
  const float* eout_b = (const float*)d_in[35];
  const float* ef1_w = (const float*)d_in[36];
  const float* ef1_b = (const float*)d_in[37];
  const float* ef2_w = (const float*)d_in[38];
  const float* ef2_b = (const float*)d_in[39];
  const float* eln1_s = (const float*)d_in[40];
  const float* eln1_b = (const float*)d_in[41];
  const float* eln2_s = (const float*)d_in[42];
  const float* eln2_b = (const float*)d_in[43];
  const float* pcat_w = (const float*)d_in[44];
  const float* pcat_b = (const float*)d_in[45];
  const float* fuse_w = (const float*)d_in[46];
  const float* fuse_b = (const float*)d_in[47];
  const float* cpx_w  = (const float*)d_in[48];
  const float* cpx_b  = (const float*)d_in[49];
  const float* dpath_w = (const float*)d_in[50];
  const float* dpath_b = (const float*)d_in[51];

  char* wsb = (char*)d_ws;
  u16* feat_h  = (u16*)(wsb + OFF_FEAT);
  u16* fe1w_h  = (u16*)(wsb + OFF_FE1W);
  float* part  = (float*)(wsb + OFF_PART);
  u16* pair    = (u16*)(wsb + OFF_PAIR);
  u16* finalb  = (u16*)(wsb + OFF_FINAL);
  u16* obj_in  = (u16*)(wsb + OFF_OBJIN);
  u16* qkvh    = (u16*)(wsb + OFF_QKVH);
  float* x     = (float*)(wsb + OFF_X);
  u16* xh      = (u16*)(wsb + OFF_XH);
  u16* attn_h  = (u16*)(wsb + OFF_ATTN);
  float* res1  = (float*)(wsb + OFF_RES);
  u16* f_h     = (u16*)(wsb + OFF_FH);
  u16* edge_in = (u16*)(wsb + OFF_EDGE);

  size_t off = P_END;
  auto alloc = [&](size_t bytes) { char* p = wsb + off; off = (off + bytes + 255) & ~(size_t)255; return p; };
  u16* wblock   = (u16*)alloc(W_WEND * 2);
  u16* catw     = (u16*)alloc(313344);
  float* biasc  = (float*)alloc(256);
  u16* bf0h     = (u16*)alloc(2621440);
  u16* gctx_h   = (u16*)alloc(65536);
  float* gcproj = (float*)alloc(262144);
  float* fpart  = (float*)alloc(4194304);

  const u16* fe2w_h   = wblock + W_FE2;
  const u16* lobjw_h  = wblock + W_LOBJ;
  const u16* ledgew_h = wblock + W_LEDGE;
  const u16* pcatw_h  = wblock + W_PCAT;
  const u16* fusew_h  = wblock + W_FUSE;

  // --- 1) converts (3 dispatches) ---
  conv_big2<<<2048, 256, 0, stream>>>(features, fe1_w, feat_h, fe1w_h);
  EncSrcs es = {fe2_w, lobj_w, ledge_w, oqkv_w, oout_w, of1_w, of2_w,
                eqkv_w, eout_w, ef1_w, ef2_w, pcat_w, fuse_w};
  conv_enc<<<2048, 256, 0, stream>>>(es, wblock);
  conv_cat<<<160, 256, 0, stream>>>(cpx_w, dpath_w, cpx_b, dpath_b, catw, biasc);

  // --- 2) fe1 split-K=8 (K-chunk == XCD, 128x128 tiles) + reduce ---
  gemm_fe1<<<dim3(8, 80), 256, 0, stream>>>(feat_h, fe1w_h, part);
  reduce8_kernel<<<(cN * cREP + 255) / 256, 256, 0, stream>>>(part, fe1_b, bf0h);

  // --- 3) box path + emb1 gather ---
  prep_obj<<<cN / 8, 256, 0, stream>>>(boxes, bb1_w, bb1_b, bb2_w, bb2_b, emb1, labels, obj_in);

  // --- 4) fe2 -> obj_in[:, :1024] ---
  g16<32, 32>(stream, bf0h, 1024, fe2w_h, 1024, cN, cREP, cREP,
              nullptr, 0, obj_in, 1408, fe2_b, nullptr, 0, 0, 1);

  // --- 5) obj_rep -> x, xh ---
  g16<32, 32>(stream, obj_in, 1408, lobjw_h, 1408, cN, cHID, 1408,
              x, 512, xh, 512, lobj_b, nullptr, 0, 0, 0);

  // --- 6) object encoder ---
  run_encoder(stream, x, xh, qkvh, attn_h, res1, f_h,
              wblock + W_OQKV, oqkv_b, wblock + W_OOUT, oout_b,
              wblock + W_OF1, of1_b, wblock + W_OF2, of2_b,
              oln1_s, oln1_b, oln2_s, oln2_b, edge_in, 768);

  // --- 7) emb2 gather + pair gather (merged) ---
  gather_pair<<<cR, 256, 0, stream>>>(emb2, labels, edge_in, relidx, pair);

  // --- 8) edge encoder ---
  g16<32, 32>(stream, edge_in, 768, ledgew_h, 768, cN, cHID, 768,
              x, 512, xh, 512, ledge_b, nullptr, 0, 0, 0);
  run_encoder(stream, x, xh, qkvh, attn_h, res1, f_h,
              wblock + W_EQKV, eqkv_b, wblock + W_EOUT, eout_b,
              wblock + W_EF1, ef1_b, wblock + W_EF2, ef2_b,
              eln1_s, eln1_b, eln2_s, eln2_b, xh, 512);
  mean_kernel<<<cB, cHID, 0, stream>>>(x, gctx_h);

  // --- 9) gcproj = gctx @ fuse_w[:,1024:]^T + fuse_b ---
  g16<32, 64>(stream, gctx_h, 512, fusew_h + 1024, 1536, 64, cREP, 512,
              gcproj, 1024, nullptr, 0, fuse_b, nullptr, 0, 0, 0);

  // --- 10) final feature block ---
  conv2d_kernel<<<cR, 256, 0, stream>>>(unionf, 1024, finalb + 1024, 3072, 1024);
  g16<128, 64>(stream, pair, 1024, pcatw_h, 1024, cR, cREP, 1024,
               nullptr, 0, finalb + 2048, 3072, pcat_b, nullptr, 0, 0, 0);
  g16<128, 64>(stream, finalb + 2048, 3072, fusew_h, 1536, cR, cREP, 1024,
               nullptr, 0, finalb, 3072, nullptr, gcproj, 1024, 2, 1);

  // --- 11) rel_logits ---
  gemm_h<64, 64, true><<<dim3(1, 64, 4), 256, 0, stream>>>(
      finalb, 3072, catw, 3072, cR, cRELC, 3072 / 4, fpart, 64,
      nullptr, 0, nullptr, nullptr, 0, 0, 0);
  freduce_kernel<<<(cR * cRELC + 255) / 256, 256, 0, stream>>>(fpart, biasc, (float*)d_out);
}